// Round 3
// baseline (987.367 us; speedup 1.0000x reference)
//
#include <hip/hip_runtime.h>
#include <hip/hip_bf16.h>
#include <cmath>

typedef __bf16 bf16;
typedef __attribute__((ext_vector_type(8))) __bf16 bf16x8;
typedef __attribute__((ext_vector_type(4))) float f32x4;
typedef unsigned int u32;
typedef unsigned short u16;

#define D_MODEL 2048
#define NH 16
#define DQ 128
#define DH 2048
#define DFFN 8192
#define DOUT 22528
#define BATCH 2
#define SEQ 2048
#define NROWS 4096

__device__ __forceinline__ void gload16(const void* g, void* l) {
    __builtin_amdgcn_global_load_lds((__attribute__((address_space(1))) const void*)g,
                                     (__attribute__((address_space(3))) void*)l, 16, 0, 0);
}

__device__ __forceinline__ float bf2f(u16 u) {
    union { u32 i; float f; } c; c.i = ((u32)u) << 16; return c.f;
}

// ---------------- fp32 -> bf16 conversion ----------------
__global__ __launch_bounds__(256) void cvt_f32_bf16(const float* __restrict__ in,
                                                    bf16* __restrict__ out) {
    size_t i = ((size_t)blockIdx.x * 256 + threadIdx.x) * 8;
    float4 a = *(const float4*)(in + i);
    float4 b = *(const float4*)(in + i + 4);
    bf16x8 o;
    o[0]=(bf16)a.x; o[1]=(bf16)a.y; o[2]=(bf16)a.z; o[3]=(bf16)a.w;
    o[4]=(bf16)b.x; o[5]=(bf16)b.y; o[6]=(bf16)b.z; o[7]=(bf16)b.w;
    *(bf16x8*)(out + i) = o;
}

// ---------------- RMSNorm (fp32 in -> bf16 out) ----------------
__global__ __launch_bounds__(256) void rmsnorm_k(const float* __restrict__ x,
                                                 const float* __restrict__ g,
                                                 bf16* __restrict__ out) {
    __shared__ float red[4];
    const int row = blockIdx.x;
    const int t = threadIdx.x;
    const float* xr = x + (size_t)row * D_MODEL;
    float4 v0 = *(const float4*)(xr + t*8);
    float4 v1 = *(const float4*)(xr + t*8 + 4);
    float ss = v0.x*v0.x + v0.y*v0.y + v0.z*v0.z + v0.w*v0.w
             + v1.x*v1.x + v1.y*v1.y + v1.z*v1.z + v1.w*v1.w;
    #pragma unroll
    for (int m = 32; m >= 1; m >>= 1) ss += __shfl_xor(ss, m);
    if ((t & 63) == 0) red[t >> 6] = ss;
    __syncthreads();
    float tot = red[0] + red[1] + red[2] + red[3];
    float norm = sqrtf(tot) * 0.022097086912079608f;   // * D^-0.5
    float inv = 1.0f / fmaxf(norm, 1e-8f);
    float4 g0 = *(const float4*)(g + t*8);
    float4 g1 = *(const float4*)(g + t*8 + 4);
    bf16x8 o;
    o[0]=(bf16)(v0.x*inv*g0.x); o[1]=(bf16)(v0.y*inv*g0.y);
    o[2]=(bf16)(v0.z*inv*g0.z); o[3]=(bf16)(v0.w*inv*g0.w);
    o[4]=(bf16)(v1.x*inv*g1.x); o[5]=(bf16)(v1.y*inv*g1.y);
    o[6]=(bf16)(v1.z*inv*g1.z); o[7]=(bf16)(v1.w*inv*g1.w);
    *(bf16x8*)(out + (size_t)row * D_MODEL + t*8) = o;
}

// ============ 256x256 8-phase BT GEMM: C[M,N] = A[M,K] * B[N,K]^T ============
// 8 waves, K-half units of 32, 4 LDS slots x 32KB, lead-3 staging, counted vmcnt.
// Swizzle: phys granule = g ^ ((row>>2)&3)  (2-way conflict = free).
#define VMW(n)  asm volatile("s_waitcnt vmcnt(" #n ")" ::: "memory")
#define LGK0()  asm volatile("s_waitcnt lgkmcnt(0)" ::: "memory")
#define BARX()  { asm volatile("" ::: "memory"); __builtin_amdgcn_s_barrier(); asm volatile("" ::: "memory"); }

#define STAGE_A(w_) { \
    const bf16* sA_ = Abase + (size_t)(w_)*32; \
    char* dA_ = smem + ((w_)&3)*32768 + wid*1024; \
    gload16(sA_, dA_); \
    gload16(sA_ + (size_t)128*K, dA_ + 8192); }

#define STAGE_B(w_) { \
    const bf16* sB_ = Bbase + (size_t)(w_)*32; \
    char* dB_ = smem + ((w_)&3)*32768 + 16384 + wid*1024; \
    gload16(sB_, dB_); \
    gload16(sB_ + (size_t)128*K, dB_ + 8192); }

// One unit = 2 phases. Unit u's data was verified landed at end of unit u-1
// (prologue for u=0). VMODD verifies unit u+1; DOSTAGE stages unit u+3.
#define UNIT_BODY(u_, VMODD, DOSTAGE) { \
    const char* base_ = smem + ((u_)&3)*32768; \
    bf16x8 bfr_[4], af_[4]; \
    _Pragma("unroll") for (int nf = 0; nf < 4; ++nf) \
        bfr_[nf] = *(const bf16x8*)(base_ + boff + nf*1024); \
    _Pragma("unroll") for (int mm = 0; mm < 4; ++mm) \
        af_[mm] = *(const bf16x8*)(base_ + aoff + mm*1024); \
    if (DOSTAGE) { STAGE_A((u_)+3); } \
    BARX(); \
    __builtin_amdgcn_s_setprio(1); \
    _Pragma("unroll") for (int mm = 0; mm < 4; ++mm) \
        _Pragma("unroll") for (int nf = 0; nf < 4; ++nf) \
            acc[mm][nf] = __builtin_amdgcn_mfma_f32_16x16x32_bf16(af_[mm], bfr_[nf], acc[mm][nf], 0, 0, 0); \
    __builtin_amdgcn_s_setprio(0); \
    LGK0(); \
    BARX(); \
    _Pragma("unroll") for (int mm = 0; mm < 4; ++mm) \
        af_[mm] = *(const bf16x8*)(base_ + aoff + 4096 + mm*1024); \
    if (DOSTAGE) { STAGE_B((u_)+3); } \
    VMODD; \
    BARX(); \
    __builtin_amdgcn_s_setprio(1); \
    _Pragma("unroll") for (int mm = 0; mm < 4; ++mm) \
        _Pragma("unroll") for (int nf = 0; nf < 4; ++nf) \
            acc[4+mm][nf] = __builtin_amdgcn_mfma_f32_16x16x32_bf16(af_[mm], bfr_[nf], acc[4+mm][nf], 0, 0, 0); \
    __builtin_amdgcn_s_setprio(0); \
    LGK0(); \
    BARX(); \
}

template<int MODE>
__global__ __launch_bounds__(512, 2) void gemm256p(
    const bf16* __restrict__ A, const bf16* __restrict__ B,
    int M, int N, int K, int nbx,
    const float* __restrict__ bias, bf16* __restrict__ outb,
    const float* __restrict__ addsrc, float* __restrict__ outf)
{
    __shared__ char smem[131072];          // 4 slots x [A 16KB | B 16KB]
    const int tid = threadIdx.x;
    const int wid = tid >> 6, lane = tid & 63;
    const int la = lane & 15, hi = lane >> 4;
    const int wm = wid >> 2, wn = wid & 3;

    // T1: bijective XCD swizzle (gridDim.x % 8 == 0)
    const int nwg = gridDim.x;
    const int cpx = nwg >> 3;
    const int bI = blockIdx.x;
    const int wg = (bI & 7) * cpx + (bI >> 3);
    const int bm = wg / nbx, bn = wg % nbx;
    const size_t m0 = (size_t)bm * 256, n0 = (size_t)bn * 256;

    // staging: lane writes LDS linearly (row = line*128 + wid*16 + (lane>>2),
    // phys granule = lane&3); source granule pre-inverse-swizzled:
    const int sg = (lane & 3) ^ (lane >> 4);
    const bf16* Abase = A + (m0 + wid*16 + (lane >> 2)) * (size_t)K + sg*8;
    const bf16* Bbase = B + (n0 + wid*16 + (lane >> 2)) * (size_t)K + sg*8;

    // read addressing: phys granule = hi ^ ((row>>2)&3), row&15 = la
    const int gsw = (hi ^ (la >> 2)) << 4;
    const int aoff = (wm*128 + la) * 64 + gsw;           // + mm*1024 (+4096 for m-hi)
    const int boff = 16384 + (wn*64 + la) * 64 + gsw;    // + nf*1024

    f32x4 acc[8][4] = {};
    const int NU = K >> 5;                 // 32-wide K units

    // prologue: stage units 0,1,2; verify unit 0 landed
    STAGE_A(0); STAGE_B(0);
    STAGE_A(1); STAGE_B(1);
    STAGE_A(2); STAGE_B(2);
    VMW(8);
    BARX();

    #pragma unroll 1
    for (int u = 0; u < NU - 3; ++u) UNIT_BODY(u, VMW(8), true);
    UNIT_BODY(NU-3, VMW(4), false);
    UNIT_BODY(NU-2, VMW(0), false);
    UNIT_BODY(NU-1, , false);

    #pragma unroll
    for (int mf = 0; mf < 8; ++mf) {
        const size_t row = m0 + wm*128 + mf*16 + hi*4;
        #pragma unroll
        for (int nf = 0; nf < 4; ++nf) {
            const size_t col = n0 + wn*64 + nf*16 + la;
            if (MODE == 0) {
                const float bv = bias[col];
                #pragma unroll
                for (int r = 0; r < 4; ++r)
                    outb[(row + r) * N + col] = (bf16)(acc[mf][nf][r] + bv);
            } else {
                #pragma unroll
                for (int r = 0; r < 4; ++r) {
                    const size_t off = (row + r) * N + col;
                    outf[off] = addsrc[off] + acc[mf][nf][r];
                }
            }
        }
    }
}

// ---------------- 128x128 BT GEMM (m97 structure) for the small GEMMs ----------------
template<int MODE>
__global__ __launch_bounds__(256) void gemm_bt(
    const bf16* __restrict__ A, const bf16* __restrict__ B,
    int M, int N, int K,
    const float* __restrict__ bias, bf16* __restrict__ outb,
    const float* __restrict__ addsrc, float* __restrict__ outf)
{
    __shared__ bf16 As[128][32];
    __shared__ bf16 Bs[128][32];
    const int tid = threadIdx.x;
    const int wid = tid >> 6, lane = tid & 63;
    const int la = lane & 15, hi = lane >> 4;
    const int m0 = blockIdx.y * 128, n0 = blockIdx.x * 128;
    const int wr = (wid >> 1) * 64, wc = (wid & 1) * 64;
    f32x4 acc[4][4] = {};
    const int idx0 = tid, idx1 = 256 + tid;
    const int r0 = idx0 >> 2, c0 = (idx0 & 3) << 3;
    const int r1 = idx1 >> 2, c1 = (idx1 & 3) << 3;
    const bf16* Ap0 = A + (size_t)(m0 + r0) * K + c0;
    const bf16* Ap1 = A + (size_t)(m0 + r1) * K + c1;
    const bf16* Bp0 = B + (size_t)(n0 + r0) * K + c0;
    const bf16* Bp1 = B + (size_t)(n0 + r1) * K + c1;
    char* asb = (char*)As + wid * 1024;
    char* bsb = (char*)Bs + wid * 1024;

    for (int k0 = 0; k0 < K; k0 += 32) {
        __syncthreads();
        gload16(Ap0 + k0, asb);
        gload16(Ap1 + k0, asb + 4096);
        gload16(Bp0 + k0, bsb);
        gload16(Bp1 + k0, bsb + 4096);
        __syncthreads();
        bf16x8 af[4], bfr[4];
        #pragma unroll
        for (int m = 0; m < 4; ++m) af[m] = *(const bf16x8*)&As[wr + m*16 + la][hi*8];
        #pragma unroll
        for (int n = 0; n < 4; ++n) bfr[n] = *(const bf16x8*)&Bs[wc + n*16 + la][hi*8];
        #pragma unroll
        for (int m = 0; m < 4; ++m)
            #pragma unroll
            for (int n = 0; n < 4; ++n)
                acc[m][n] = __builtin_amdgcn_mfma_f32_16x16x32_bf16(af[m], bfr[n], acc[m][n], 0, 0, 0);
    }

    #pragma unroll
    for (int m = 0; m < 4; ++m) {
        const int row = m0 + wr + m*16 + hi*4;
        #pragma unroll
        for (int n = 0; n < 4; ++n) {
            const int col = n0 + wc + n*16 + la;
            if (MODE == 0) {
                const float bv = bias[col];
                #pragma unroll
                for (int r = 0; r < 4; ++r)
                    outb[(size_t)(row + r) * N + col] = (bf16)(acc[m][n][r] + bv);
            } else {
                #pragma unroll
                for (int r = 0; r < 4; ++r) {
                    const size_t off = (size_t)(row + r) * N + col;
                    outf[off] = addsrc[off] + acc[m][n][r];
                }
            }
        }
    }
}

// ---------------- RoPE table ----------------
__global__ __launch_bounds__(256) void rope_table(float* __restrict__ ctab,
                                                  float* __restrict__ stab) {
    int idx = blockIdx.x * 256 + threadIdx.x;     // l*64 + i
    int l = idx >> 6, i = idx & 63;
    float inv = powf(10000.0f, -(float)i / 64.0f);
    float ang = (float)l * inv;
    float s, c;
    sincosf(ang, &s, &c);
    ctab[idx] = c; stab[idx] = s;
}

__device__ __forceinline__ u32 rope_pair(u32 u, float c, float s) {
    float t1 = bf2f((u16)(u & 0xffff));
    float t2 = bf2f((u16)(u >> 16));
    float r1 = t1 * c - t2 * s;
    float r2 = t1 * s + t2 * c;
    bf16 b1 = (bf16)r1, b2 = (bf16)r2;
    return (u32)__builtin_bit_cast(u16, b1) | ((u32)__builtin_bit_cast(u16, b2) << 16);
}

// ---------------- q/k rope + reshape to [B,H,L,128] ----------------
__global__ __launch_bounds__(256) void rope_qk(const bf16* __restrict__ h,
                                               const float* __restrict__ ctab,
                                               const float* __restrict__ stab,
                                               bf16* __restrict__ qb, bf16* __restrict__ kb) {
    int idx = blockIdx.x * 256 + threadIdx.x;     // (((b*2048+l)*16 + hh)*64 + i)
    int i  = idx & 63;
    int hh = (idx >> 6) & 15;
    int l  = (idx >> 10) & 2047;
    int b  = idx >> 21;
    size_t hrow = (size_t)(b * SEQ + l) * DOUT;
    float c = ctab[l*64 + i], s = stab[l*64 + i];
    u32 uq = *(const u32*)(h + hrow + hh*DQ + 2*i);
    u32 uk = *(const u32*)(h + hrow + DH + hh*DQ + 2*i);
    size_t orow = ((size_t)(b*NH + hh) * SEQ + l) * DQ + 2*i;
    *(u32*)(qb + orow) = rope_pair(uq, c, s);
    *(u32*)(kb + orow) = rope_pair(uk, c, s);
}

// ---------------- V transpose: h_bf16 v-section -> vt [B,H,128,L] ----------------
__global__ __launch_bounds__(256) void v_transpose(const bf16* __restrict__ h,
                                                   bf16* __restrict__ vt) {
    __shared__ u32 lds[64][68];
    const int lt = blockIdx.x, bh = blockIdx.y;
    const int b = bh >> 4, hh = bh & 15;
    const int t = threadIdx.x;
    const bf16* src = h + (size_t)(b * SEQ + lt * 64) * DOUT + 2*DH + hh * DQ;
    #pragma unroll
    for (int i = 0; i < 4; ++i) {
        int j = i*256 + t;
        int l = j >> 4, ch = j & 15;
        uint4 v = *(const uint4*)(src + (size_t)l * DOUT + ch*8);
        *(uint4*)&lds[l][ch*4] = v;
    }
    __syncthreads();
    bf16* dst = vt + (size_t)bh * DQ * SEQ + lt * 64;
    #pragma unroll
    for (int i = 0; i < 4; ++i) {
        int j = i*256 + t;
        int d = j >> 3, lc = j & 7;
        u32 out[4];
        #pragma unroll
        for (int m = 0; m < 4; ++m) {
            u32 a0 = lds[lc*8 + 2*m][d >> 1];
            u32 a1 = lds[lc*8 + 2*m + 1][d >> 1];
            u16 s0 = (d & 1) ? (u16)(a0 >> 16) : (u16)(a0 & 0xffff);
            u16 s1 = (d & 1) ? (u16)(a1 >> 16) : (u16)(a1 & 0xffff);
            out[m] = (u32)s0 | ((u32)s1 << 16);
        }
        *(uint4*)(dst + (size_t)d * SEQ + lc*8) = *(uint4*)out;
    }
}

// ---------------- SwiGLU: ag = a * silu(b) ----------------
__global__ __launch_bounds__(256) void silu_k(const bf16* __restrict__ h,
                                              bf16* __restrict__ ag) {
    size_t idx = ((size_t)blockIdx.x * 256 + threadIdx.x) * 8;
    int r = (int)(idx >> 13);
    int f = (int)(idx & 8191);
    const bf16* hr = h + (size_t)r * DOUT + 3*DH;
    bf16x8 va = *(const bf16x8*)(hr + f);
    bf16x8 vb = *(const bf16x8*)(hr + DFFN + f);
    bf16x8 o;
    #pragma unroll
    for (int j = 0; j < 8; ++j) {
        float a = (float)va[j];
        float b = (float)vb[j];
        float sil = b / (1.0f + __expf(-b));
        o[j] = (bf16)(a * sil);
    }
    *(bf16x8*)(ag + idx) = o;
}

// ---------------- causal flash attention ----------------
__global__ __launch_bounds__(256) void attn_fa(const bf16* __restrict__ Q,
                                               const bf16* __restrict__ Kb,
                                               const bf16* __restrict__ Vt,
                                               bf16* __restrict__ O) {
    __shared__ bf16 Ks[64][128];
    __shared__ bf16 Vts[128][64];
    __shared__ bf16 Ps[4][16][64];
    const int qt = blockIdx.x, bh = blockIdx.y;
    const int b = bh >> 4, hh = bh & 15;
    const int tid = threadIdx.x, wid = tid >> 6, lane = tid & 63;
    const int la = lane & 15, hi = lane >> 4;
    const bf16* Qp = Q + (size_t)bh * SEQ * DQ;
    const bf16* Kp = Kb + (size_t)bh * SEQ * DQ;
    const bf16* Vp = Vt + (size_t)bh * DQ * SEQ;
    const int q0w = qt * 64 + wid * 16;

    bf16x8 qf[4];
    #pragma unroll
    for (int s = 0; s < 4; ++s)
        qf[s] = *(const bf16x8*)(Qp + (size_t)(q0w + la) * DQ + s*32 + hi*8);

    f32x4 acc_o[8] = {};
    float m_run[4] = {-1e30f, -1e30f, -1e30f, -1e30f};
    float l_run[4] = {0.f, 0.f, 0.f, 0.f};
    const float scale = 0.08838834764831845f;

    const int nk = qt + 1;
    for (int kt = 0; kt < nk; ++kt) {
        const int k0 = kt * 64;
        __syncthreads();
        #pragma unroll
        for (int i = 0; i < 4; ++i) {
            int j = i*256 + tid;
            int kr = j >> 4, jg = j & 15;               // K tile: row, 16B granule
            gload16(Kp + (size_t)(k0 + kr) * DQ + ((jg ^ (kr & 7)) << 3),
                    (char*)Ks + i*4096 + wid*1024);
            int d = j >> 3, vg = j & 7;                 // Vt tile: row d, granule
            gload16(Vp + (size_t)d * SEQ + k0 + ((vg ^ (d & 7)) << 3),
                    (char*)Vts + i*4096 + wid*1024);
        }
        __syncthreads();

        f32x4 sacc[4] = {};
        __builtin_amdgcn_s_setprio(1);
        #pragma unroll
        for (int g = 0; g < 4; ++g) {
            const int krow = g*16 + la;
            #pragma unroll
            for (int s = 0; s < 4; ++s) {
                bf16x8 kf = *(const bf16x8*)((const char*)Ks + krow*256 + (((s*4 + hi) ^ (la & 7)) << 4));
                sacc[g] = __builtin_amdgcn_mfma_f32_16x16x32_bf16(qf[s], kf, sacc[g], 0, 0, 0);
            }
        }
        __builtin_amdgcn_s_setprio(0);

        float mnew[4];
        #pragma unroll
        for (int r = 0; r < 4; ++r) mnew[r] = m_run[r];
        #pragma unroll
        for (int g = 0; g < 4; ++g)
            #pragma unroll
            for (int r = 0; r < 4; ++r) {
                float sv = sacc[g][r] * scale;
                int qi = q0w + hi*4 + r;
                int ki = k0 + g*16 + la;
                sv = (ki <= qi) ? sv : -1e30f;
                sacc[g][r] = sv;
                mnew[r] = fmaxf(mnew[r], sv);
            }
        #pragma unroll
        for (int r = 0; r < 4; ++r) {
            float v = mnew[r];
            v = fmaxf(v, __shfl_xor(v, 1));
            v = fmaxf(v, __shfl_xor(v, 2));
            v = fmaxf(v, __shfl_xor(v, 4));
            v = fmaxf(v, __shfl_xor(v, 8));
            mnew[r] = v;
        }
        float resc[4], lsum[4];
        #pragma unroll
        for (int r = 0; r < 4; ++r) {
            resc[r] = __expf(m_run[r] - mnew[r]);
            m_run[r] = mnew[r];
            lsum[r] = 0.f;
        }
        #pragma unroll
        for (int g = 0; g < 4; ++g)
            #pragma unroll
            for (int r = 0; r < 4; ++r) {
                float p = __expf(sacc[g][r] - mnew[r]);
                sacc[g][r] = p;
                lsum[r] += p;
            }
        #pragma unroll
        for (int r = 0; r < 4; ++r) {
            float v = lsum[r];
            v += __shfl_xor(v, 1); v += __shfl_xor(v, 2);
            v += __shfl_xor(v, 4); v += __shfl_xor(v, 8);
            l_run[r] = l_run[r] * resc[r] + v;
        }
        #pragma unroll
        for (int g = 0; g < 4; ++g)
            #pragma unroll
            for (int r = 0; r < 4; ++r) {
                int prow = hi*4 + r;
                int pcol = (g*16 + la) ^ ((prow & 7) << 3);
                Ps[wid][prow][pcol] = (bf16)sacc[g][r];
            }
        #pragma unroll
        for (int n = 0; n < 8; ++n)
            #pragma unroll
            for (int r = 0; r < 4; ++r) acc_o[n][r] *= resc[r];
        __builtin_amdgcn_s_setprio(1);
        #pragma unroll
        for (int kk = 0; kk < 2; ++kk) {
            bf16x8 pf = *(const bf16x8*)((const char*)&Ps[wid][0][0] + la*128 +
                                         (((kk*32 + hi*8) ^ ((la & 7) << 3)) << 1));
            #pragma unroll
            for (int n = 0; n < 8; ++n) {
                const int vrow = n*16 + la;
                bf16x8 vf = *(const bf16x8*)((const char*)Vts + vrow*128 + (((kk*4 + hi) ^ (la & 7)) << 4));
                acc_o[n] = __builtin_amdgcn_mfma_f32_16x16x32_bf16(pf, vf, acc_o[n], 0, 0, 0);
            }
        }
        __builtin_amdgcn_s_setprio(0);
    }

    bf16* Op = O + (size_t)b * SEQ * DH + (size_t)hh * DQ;
    #pragma unroll
    for (int r = 0; r < 4; ++r) {
        int qi = q0w + hi*4 + r;
        float invl = 1.0f / l_run[r];
        #pragma unroll
        for (int n = 0; n < 8; ++n)
            Op[(size_t)qi * DH + n*16 + la] = (bf16)(acc_o[n][r] * invl);
    }
}

// ---------------- launch ----------------
extern "C" void kernel_launch(void* const* d_in, const int* in_sizes, int n_in,
                              void* d_out, int out_size, void* d_ws, size_t ws_size,
                              hipStream_t stream) {
    const float* x       = (const float*)d_in[0];
    const float* g       = (const float*)d_in[1];
    const float* W_dense = (const float*)d_in[2];
    const float* b_dense = (const float*)d_in[3];
    const float* W_attn  = (const float*)d_in[4];
    const float* W_ffn   = (const float*)d_in[5];
    float* out = (float*)d_out;

    char* ws = (char*)d_ws;
    bf16* normed  = (bf16*)(ws + 0);                    // 16.8 MB (reused as attn_buf)
    bf16* Wd_b    = (bf16*)(ws + 16777216);             // 92.3 MB (reused as q/k/vt)
    bf16* Wa_b    = (bf16*)(ws + 109051904);             // 8.4 MB
    bf16* Wf_b    = (bf16*)(ws + 117440512);            // 33.6 MB
    bf16* h_b     = (bf16*)(ws + 150994944);            // 184.5 MB
    bf16* ag_b    = (bf16*)(ws + 335544320);            // 67.1 MB
    float* ctab   = (float*)(ws + 402653184);           // 0.5 MB
    float* stab   = (float*)(ws + 403177472);           // 0.5 MB
    bf16* q_b  = (bf16*)(ws + 16777216);
    bf16* k_b  = (bf16*)(ws + 16777216 + 16777216);
    bf16* vt_b = (bf16*)(ws + 16777216 + 33554432);
    bf16* attn_b = normed;

    cvt_f32_bf16<<<46137344/2048, 256, 0, stream>>>(W_dense, Wd_b);
    cvt_f32_bf16<<<4194304/2048, 256, 0, stream>>>(W_attn, Wa_b);
    cvt_f32_bf16<<<16777216/2048, 256, 0, stream>>>(W_ffn, Wf_b);
    rmsnorm_k<<<NROWS, 256, 0, stream>>>(x, g, normed);
    // dense GEMM -> h (bf16, +bias): 256^2 8-phase kernel
    {
        dim3 grid((NROWS/256) * (DOUT/256));            // 16*88 = 1408, %8==0
        gemm256p<0><<<grid, 512, 0, stream>>>(normed, Wd_b, NROWS, DOUT, D_MODEL,
                                              DOUT/256, b_dense, h_b, nullptr, nullptr);
    }
    rope_table<<<SEQ*64/256, 256, 0, stream>>>(ctab, stab);
    rope_qk<<<4194304/256, 256, 0, stream>>>(h_b, ctab, stab, q_b, k_b);
    {
        dim3 grid(SEQ/64, BATCH*NH);
        v_transpose<<<grid, 256, 0, stream>>>(h_b, vt_b);
    }
    silu_k<<<(size_t)NROWS*DFFN/8/256, 256, 0, stream>>>(h_b, ag_b);
    {
        dim3 grid(SEQ/64, BATCH*NH);
        attn_fa<<<grid, 256, 0, stream>>>(q_b, k_b, vt_b, attn_b);
    }
    {
        dim3 grid(D_MODEL/128, NROWS/128);
        gemm_bt<1><<<grid, 256, 0, stream>>>(attn_b, Wa_b, NROWS, D_MODEL, DH,
                                             nullptr, nullptr, x, out);
    }
    {
        dim3 grid(D_MODEL/128, NROWS/128);
        gemm_bt<1><<<grid, 256, 0, stream>>>(ag_b, Wf_b, NROWS, D_MODEL, DFFN,
                                             nullptr, nullptr, out, out);
    }
}

// Round 4
// 952.781 us; speedup vs baseline: 1.0363x; 1.0363x over previous
//
#include <hip/hip_runtime.h>
#include <hip/hip_bf16.h>
#include <cmath>

typedef __bf16 bf16;
typedef __attribute__((ext_vector_type(8))) __bf16 bf16x8;
typedef __attribute__((ext_vector_type(4))) float f32x4;
typedef unsigned int u32;
typedef unsigned short u16;

#define D_MODEL 2048
#define NH 16
#define DQ 128
#define DH 2048
#define DFFN 8192
#define DOUT 22528
#define BATCH 2
#define SEQ 2048
#define NROWS 4096

__device__ __forceinline__ void gload16(const void* g, void* l) {
    __builtin_amdgcn_global_load_lds((__attribute__((address_space(1))) const void*)g,
                                     (__attribute__((address_space(3))) void*)l, 16, 0, 0);
}

__device__ __forceinline__ float bf2f(u16 u) {
    union { u32 i; float f; } c; c.i = ((u32)u) << 16; return c.f;
}

// ---------------- fp32 -> bf16 conversion ----------------
__global__ __launch_bounds__(256) void cvt_f32_bf16(const float* __restrict__ in,
                                                    bf16* __restrict__ out) {
    size_t i = ((size_t)blockIdx.x * 256 + threadIdx.x) * 8;
    float4 a = *(const float4*)(in + i);
    float4 b = *(const float4*)(in + i + 4);
    bf16x8 o;
    o[0]=(bf16)a.x; o[1]=(bf16)a.y; o[2]=(bf16)a.z; o[3]=(bf16)a.w;
    o[4]=(bf16)b.x; o[5]=(bf16)b.y; o[6]=(bf16)b.z; o[7]=(bf16)b.w;
    *(bf16x8*)(out + i) = o;
}

// ---------------- RMSNorm (fp32 in -> bf16 out) ----------------
__global__ __launch_bounds__(256) void rmsnorm_k(const float* __restrict__ x,
                                                 const float* __restrict__ g,
                                                 bf16* __restrict__ out) {
    __shared__ float red[4];
    const int row = blockIdx.x;
    const int t = threadIdx.x;
    const float* xr = x + (size_t)row * D_MODEL;
    float4 v0 = *(const float4*)(xr + t*8);
    float4 v1 = *(const float4*)(xr + t*8 + 4);
    float ss = v0.x*v0.x + v0.y*v0.y + v0.z*v0.z + v0.w*v0.w
             + v1.x*v1.x + v1.y*v1.y + v1.z*v1.z + v1.w*v1.w;
    #pragma unroll
    for (int m = 32; m >= 1; m >>= 1) ss += __shfl_xor(ss, m);
    if ((t & 63) == 0) red[t >> 6] = ss;
    __syncthreads();
    float tot = red[0] + red[1] + red[2] + red[3];
    float norm = sqrtf(tot) * 0.022097086912079608f;   // * D^-0.5
    float inv = 1.0f / fmaxf(norm, 1e-8f);
    float4 g0 = *(const float4*)(g + t*8);
    float4 g1 = *(const float4*)(g + t*8 + 4);
    bf16x8 o;
    o[0]=(bf16)(v0.x*inv*g0.x); o[1]=(bf16)(v0.y*inv*g0.y);
    o[2]=(bf16)(v0.z*inv*g0.z); o[3]=(bf16)(v0.w*inv*g0.w);
    o[4]=(bf16)(v1.x*inv*g1.x); o[5]=(bf16)(v1.y*inv*g1.y);
    o[6]=(bf16)(v1.z*inv*g1.z); o[7]=(bf16)(v1.w*inv*g1.w);
    *(bf16x8*)(out + (size_t)row * D_MODEL + t*8) = o;
}

// ============ 256x256 fine-phase BT GEMM: C[M,N] = A[M,K] * B[N,K]^T ============
// 8 waves, BK=64, 2x64KB LDS dbuf, R2's proven 0-conflict swizzle (128B rows,
// granule16 ^= row&7), 4 phases/tile, line-granular staging with counted vmcnt:
//   stage order for tile t+1 during tile t: p0:{A0,A2} p1:{B0,B1} p2:{B2,B3} p3:{A1,A3}
//   vmcnt(4) @p1-end guards tile t's A1,A3 (read at p2/p3)
//   vmcnt(2) @p3-end guards tile t+1's lines A0,A2,B0..B3 (read at p0/p1)
#define VMW(n)  asm volatile("s_waitcnt vmcnt(" #n ")" ::: "memory")
#define LGK0()  asm volatile("s_waitcnt lgkmcnt(0)" ::: "memory")
#define BARX()  { asm volatile("" ::: "memory"); __builtin_amdgcn_s_barrier(); asm volatile("" ::: "memory"); }

// stage line c (64 rows) of tile t_ ; A region at +0, B at +32768 of 64KB buf
#define SLINE_A(c_, t_) \
    gload16(Asrc + (size_t)((c_)*64)*K + (size_t)(t_)*64, \
            smem + (((t_)&1)<<16) + (c_)*8192 + wid*1024);
#define SLINE_B(c_, t_) \
    gload16(Bsrc + (size_t)((c_)*64)*K + (size_t)(t_)*64, \
            smem + (((t_)&1)<<16) + 32768 + (c_)*8192 + wid*1024);

#define PH_READS_B() \
    _Pragma("unroll") for (int n = 0; n < 4; ++n) { \
        const char* p_ = bb + (wn*64 + n*16 + la) * 128; \
        bfr[n][0] = *(const bf16x8*)(p_ + pg0); \
        bfr[n][1] = *(const bf16x8*)(p_ + pg1); }

#define PH_READS_A(qd_) \
    _Pragma("unroll") for (int mm = 0; mm < 2; ++mm) { \
        const char* p_ = ab + (wm*128 + ((qd_)*2 + mm)*16 + la) * 128; \
        af[mm][0] = *(const bf16x8*)(p_ + pg0); \
        af[mm][1] = *(const bf16x8*)(p_ + pg1); }

#define PH_MFMA(qd_) \
    __builtin_amdgcn_s_setprio(1); \
    _Pragma("unroll") for (int mm = 0; mm < 2; ++mm) \
        _Pragma("unroll") for (int n = 0; n < 4; ++n) { \
            acc[(qd_)*2+mm][n] = __builtin_amdgcn_mfma_f32_16x16x32_bf16(af[mm][0], bfr[n][0], acc[(qd_)*2+mm][n], 0, 0, 0); \
            acc[(qd_)*2+mm][n] = __builtin_amdgcn_mfma_f32_16x16x32_bf16(af[mm][1], bfr[n][1], acc[(qd_)*2+mm][n], 0, 0, 0); } \
    __builtin_amdgcn_s_setprio(0);

template<int MODE>
__global__ __launch_bounds__(512, 2) void gemm256f(
    const bf16* __restrict__ A, const bf16* __restrict__ B,
    int M, int N, int K, int nbx,
    const float* __restrict__ bias, bf16* __restrict__ outb,
    const float* __restrict__ addsrc, float* __restrict__ outf)
{
    __shared__ char smem[131072];          // 2 buf x [A 32KB | B 32KB]
    const int tid = threadIdx.x;
    const int wid = tid >> 6, lane = tid & 63;
    const int la = lane & 15, hi = lane >> 4;
    const int wm = wid >> 2, wn = wid & 3;

    // T1: bijective XCD swizzle (gridDim.x % 8 == 0)
    const int nwg = gridDim.x;
    const int cpx = nwg >> 3;
    const int bI = blockIdx.x;
    const int wg = (bI & 7) * cpx + (bI >> 3);
    const int bm = wg / nbx, bn = wg % nbx;
    const size_t m0 = (size_t)bm * 256, n0 = (size_t)bn * 256;

    // staging: thread covers row (c*64 + wid*8 + (lane>>3)), phys granule lane&7;
    // source granule pre-inverse-swizzled: sg = (lane&7) ^ (lane>>3)  [row&7 = lane>>3]
    const int lr = lane >> 3, lg = lane & 7;
    const int sg = lg ^ lr;
    const bf16* Asrc = A + (m0 + wid*8 + lr) * (size_t)K + sg*8;
    const bf16* Bsrc = B + (n0 + wid*8 + lr) * (size_t)K + sg*8;

    // read: phys granule = (kk*4 + hi) ^ (row&7), row&7 = la&7
    const int pg0 = (hi ^ (la & 7)) << 4;
    const int pg1 = ((4 + hi) ^ (la & 7)) << 4;

    f32x4 acc[8][4] = {};
    const int NT = K >> 6;

    // prologue: stage tile 0 in chronological line order, verify first 6 lines
    SLINE_A(0,0); SLINE_A(2,0);
    SLINE_B(0,0); SLINE_B(1,0);
    SLINE_B(2,0); SLINE_B(3,0);
    SLINE_A(1,0); SLINE_A(3,0);
    VMW(2);
    BARX();

    bf16x8 bfr[4][2];
    bf16x8 af[2][2];

    #pragma unroll 1
    for (int t = 0; t < NT - 1; ++t) {
        const char* ab = smem + ((t & 1) << 16);
        const char* bb = ab + 32768;
        const int nx = t + 1;
        // phase 0
        PH_READS_B(); PH_READS_A(0);
        SLINE_A(0,nx); SLINE_A(2,nx);
        BARX(); LGK0(); PH_MFMA(0); BARX();
        // phase 1
        PH_READS_A(1);
        SLINE_B(0,nx); SLINE_B(1,nx);
        BARX(); LGK0(); PH_MFMA(1); VMW(4); BARX();
        // phase 2
        PH_READS_A(2);
        SLINE_B(2,nx); SLINE_B(3,nx);
        BARX(); LGK0(); PH_MFMA(2); BARX();
        // phase 3
        PH_READS_A(3);
        SLINE_A(1,nx); SLINE_A(3,nx);
        BARX(); LGK0(); PH_MFMA(3); VMW(2); BARX();
    }
    {   // last tile: no staging; drain guard at p1
        const int t = NT - 1;
        const char* ab = smem + ((t & 1) << 16);
        const char* bb = ab + 32768;
        PH_READS_B(); PH_READS_A(0);
        BARX(); LGK0(); PH_MFMA(0); BARX();
        PH_READS_A(1);
        BARX(); LGK0(); PH_MFMA(1); VMW(0); BARX();
        PH_READS_A(2);
        BARX(); LGK0(); PH_MFMA(2); BARX();
        PH_READS_A(3);
        BARX(); LGK0(); PH_MFMA(3); BARX();
    }

    #pragma unroll
    for (int mf = 0; mf < 8; ++mf) {
        const size_t row = m0 + wm*128 + mf*16 + hi*4;
        #pragma unroll
        for (int nf = 0; nf < 4; ++nf) {
            const size_t col = n0 + wn*64 + nf*16 + la;
            if (MODE == 0) {
                const float bv = bias[col];
                #pragma unroll
                for (int r = 0; r < 4; ++r)
                    outb[(row + r) * N + col] = (bf16)(acc[mf][nf][r] + bv);
            } else {
                #pragma unroll
                for (int r = 0; r < 4; ++r) {
                    const size_t off = (row + r) * N + col;
                    outf[off] = addsrc[off] + acc[mf][nf][r];
                }
            }
        }
    }
}

// ---------------- 128x128 BT GEMM (m97 structure) for the small GEMMs ----------------
template<int MODE>
__global__ __launch_bounds__(256) void gemm_bt(
    const bf16* __restrict__ A, const bf16* __restrict__ B,
    int M, int N, int K,
    const float* __restrict__ bias, bf16* __restrict__ outb,
    const float* __restrict__ addsrc, float* __restrict__ outf)
{
    __shared__ bf16 As[128][32];
    __shared__ bf16 Bs[128][32];
    const int tid = threadIdx.x;
    const int wid = tid >> 6, lane = tid & 63;
    const int la = lane & 15, hi = lane >> 4;
    const int m0 = blockIdx.y * 128, n0 = blockIdx.x * 128;
    const int wr = (wid >> 1) * 64, wc = (wid & 1) * 64;
    f32x4 acc[4][4] = {};
    const int idx0 = tid, idx1 = 256 + tid;
    const int r0 = idx0 >> 2, c0 = (idx0 & 3) << 3;
    const int r1 = idx1 >> 2, c1 = (idx1 & 3) << 3;
    const bf16* Ap0 = A + (size_t)(m0 + r0) * K + c0;
    const bf16* Ap1 = A + (size_t)(m0 + r1) * K + c1;
    const bf16* Bp0 = B + (size_t)(n0 + r0) * K + c0;
    const bf16* Bp1 = B + (size_t)(n0 + r1) * K + c1;
    char* asb = (char*)As + wid * 1024;
    char* bsb = (char*)Bs + wid * 1024;

    for (int k0 = 0; k0 < K; k0 += 32) {
        __syncthreads();
        gload16(Ap0 + k0, asb);
        gload16(Ap1 + k0, asb + 4096);
        gload16(Bp0 + k0, bsb);
        gload16(Bp1 + k0, bsb + 4096);
        __syncthreads();
        bf16x8 af[4], bfr[4];
        #pragma unroll
        for (int m = 0; m < 4; ++m) af[m] = *(const bf16x8*)&As[wr + m*16 + la][hi*8];
        #pragma unroll
        for (int n = 0; n < 4; ++n) bfr[n] = *(const bf16x8*)&Bs[wc + n*16 + la][hi*8];
        #pragma unroll
        for (int m = 0; m < 4; ++m)
            #pragma unroll
            for (int n = 0; n < 4; ++n)
                acc[m][n] = __builtin_amdgcn_mfma_f32_16x16x32_bf16(af[m], bfr[n], acc[m][n], 0, 0, 0);
    }

    #pragma unroll
    for (int m = 0; m < 4; ++m) {
        const int row = m0 + wr + m*16 + hi*4;
        #pragma unroll
        for (int n = 0; n < 4; ++n) {
            const int col = n0 + wc + n*16 + la;
            if (MODE == 0) {
                const float bv = bias[col];
                #pragma unroll
                for (int r = 0; r < 4; ++r)
                    outb[(size_t)(row + r) * N + col] = (bf16)(acc[m][n][r] + bv);
            } else {
                #pragma unroll
                for (int r = 0; r < 4; ++r) {
                    const size_t off = (size_t)(row + r) * N + col;
                    outf[off] = addsrc[off] + acc[m][n][r];
                }
            }
        }
    }
}

// ---------------- RoPE table ----------------
__global__ __launch_bounds__(256) void rope_table(float* __restrict__ ctab,
                                                  float* __restrict__ stab) {
    int idx = blockIdx.x * 256 + threadIdx.x;     // l*64 + i
    int l = idx >> 6, i = idx & 63;
    float inv = powf(10000.0f, -(float)i / 64.0f);
    float ang = (float)l * inv;
    float s, c;
    sincosf(ang, &s, &c);
    ctab[idx] = c; stab[idx] = s;
}

__device__ __forceinline__ u32 rope_pair(u32 u, float c, float s) {
    float t1 = bf2f((u16)(u & 0xffff));
    float t2 = bf2f((u16)(u >> 16));
    float r1 = t1 * c - t2 * s;
    float r2 = t1 * s + t2 * c;
    bf16 b1 = (bf16)r1, b2 = (bf16)r2;
    return (u32)__builtin_bit_cast(u16, b1) | ((u32)__builtin_bit_cast(u16, b2) << 16);
}

// ---------------- q/k rope + reshape to [B,H,L,128] ----------------
__global__ __launch_bounds__(256) void rope_qk(const bf16* __restrict__ h,
                                               const float* __restrict__ ctab,
                                               const float* __restrict__ stab,
                                               bf16* __restrict__ qb, bf16* __restrict__ kb) {
    int idx = blockIdx.x * 256 + threadIdx.x;     // (((b*2048+l)*16 + hh)*64 + i)
    int i  = idx & 63;
    int hh = (idx >> 6) & 15;
    int l  = (idx >> 10) & 2047;
    int b  = idx >> 21;
    size_t hrow = (size_t)(b * SEQ + l) * DOUT;
    float c = ctab[l*64 + i], s = stab[l*64 + i];
    u32 uq = *(const u32*)(h + hrow + hh*DQ + 2*i);
    u32 uk = *(const u32*)(h + hrow + DH + hh*DQ + 2*i);
    size_t orow = ((size_t)(b*NH + hh) * SEQ + l) * DQ + 2*i;
    *(u32*)(qb + orow) = rope_pair(uq, c, s);
    *(u32*)(kb + orow) = rope_pair(uk, c, s);
}

// ---------------- V transpose: h_bf16 v-section -> vt [B,H,128,L] ----------------
__global__ __launch_bounds__(256) void v_transpose(const bf16* __restrict__ h,
                                                   bf16* __restrict__ vt) {
    __shared__ u32 lds[64][68];
    const int lt = blockIdx.x, bh = blockIdx.y;
    const int b = bh >> 4, hh = bh & 15;
    const int t = threadIdx.x;
    const bf16* src = h + (size_t)(b * SEQ + lt * 64) * DOUT + 2*DH + hh * DQ;
    #pragma unroll
    for (int i = 0; i < 4; ++i) {
        int j = i*256 + t;
        int l = j >> 4, ch = j & 15;
        uint4 v = *(const uint4*)(src + (size_t)l * DOUT + ch*8);
        *(uint4*)&lds[l][ch*4] = v;
    }
    __syncthreads();
    bf16* dst = vt + (size_t)bh * DQ * SEQ + lt * 64;
    #pragma unroll
    for (int i = 0; i < 4; ++i) {
        int j = i*256 + t;
        int d = j >> 3, lc = j & 7;
        u32 out[4];
        #pragma unroll
        for (int m = 0; m < 4; ++m) {
            u32 a0 = lds[lc*8 + 2*m][d >> 1];
            u32 a1 = lds[lc*8 + 2*m + 1][d >> 1];
            u16 s0 = (d & 1) ? (u16)(a0 >> 16) : (u16)(a0 & 0xffff);
            u16 s1 = (d & 1) ? (u16)(a1 >> 16) : (u16)(a1 & 0xffff);
            out[m] = (u32)s0 | ((u32)s1 << 16);
        }
        *(uint4*)(dst + (size_t)d * SEQ + lc*8) = *(uint4*)out;
    }
}

// ---------------- SwiGLU: ag = a * silu(b) ----------------
__global__ __launch_bounds__(256) void silu_k(const bf16* __restrict__ h,
                                              bf16* __restrict__ ag) {
    size_t idx = ((size_t)blockIdx.x * 256 + threadIdx.x) * 8;
    int r = (int)(idx >> 13);
    int f = (int)(idx & 8191);
    const bf16* hr = h + (size_t)r * DOUT + 3*DH;
    bf16x8 va = *(const bf16x8*)(hr + f);
    bf16x8 vb = *(const bf16x8*)(hr + DFFN + f);
    bf16x8 o;
    #pragma unroll
    for (int j = 0; j < 8; ++j) {
        float a = (float)va[j];
        float b = (float)vb[j];
        float sil = b / (1.0f + __expf(-b));
        o[j] = (bf16)(a * sil);
    }
    *(bf16x8*)(ag + idx) = o;
}

// ---------------- causal flash attention ----------------
__global__ __launch_bounds__(256) void attn_fa(const bf16* __restrict__ Q,
                                               const bf16* __restrict__ Kb,
                                               const bf16* __restrict__ Vt,
                                               bf16* __restrict__ O) {
    __shared__ bf16 Ks[64][128];
    __shared__ bf16 Vts[128][64];
    __shared__ bf16 Ps[4][16][64];
    const int qt = blockIdx.x, bh = blockIdx.y;
    const int b = bh >> 4, hh = bh & 15;
    const int tid = threadIdx.x, wid = tid >> 6, lane = tid & 63;
    const int la = lane & 15, hi = lane >> 4;
    const bf16* Qp = Q + (size_t)bh * SEQ * DQ;
    const bf16* Kp = Kb + (size_t)bh * SEQ * DQ;
    const bf16* Vp = Vt + (size_t)bh * DQ * SEQ;
    const int q0w = qt * 64 + wid * 16;

    bf16x8 qf[4];
    #pragma unroll
    for (int s = 0; s < 4; ++s)
        qf[s] = *(const bf16x8*)(Qp + (size_t)(q0w + la) * DQ + s*32 + hi*8);

    f32x4 acc_o[8] = {};
    float m_run[4] = {-1e30f, -1e30f, -1e30f, -1e30f};
    float l_run[4] = {0.f, 0.f, 0.f, 0.f};
    const float scale = 0.08838834764831845f;

    const int nk = qt + 1;
    for (int kt = 0; kt < nk; ++kt) {
        const int k0 = kt * 64;
        __syncthreads();
        #pragma unroll
        for (int i = 0; i < 4; ++i) {
            int j = i*256 + tid;
            int kr = j >> 4, jg = j & 15;               // K tile: row, 16B granule
            gload16(Kp + (size_t)(k0 + kr) * DQ + ((jg ^ (kr & 7)) << 3),
                    (char*)Ks + i*4096 + wid*1024);
            int d = j >> 3, vg = j & 7;                 // Vt tile: row d, granule
            gload16(Vp + (size_t)d * SEQ + k0 + ((vg ^ (d & 7)) << 3),
                    (char*)Vts + i*4096 + wid*1024);
        }
        __syncthreads();

        f32x4 sacc[4] = {};
        __builtin_amdgcn_s_setprio(1);
        #pragma unroll
        for (int g = 0; g < 4; ++g) {
            const int krow = g*16 + la;
            #pragma unroll
            for (int s = 0; s < 4; ++s) {
                bf16x8 kf = *(const bf16x8*)((const char*)Ks + krow*256 + (((s*4 + hi) ^ (la & 7)) << 4));
                sacc[g] = __builtin_amdgcn_mfma_f32_16x16x32_bf16(qf[s], kf, sacc[g], 0, 0, 0);
            }
        }
        __builtin_amdgcn_s_setprio(0);

        float mnew[4];
        #pragma unroll
        for (int r = 0; r < 4; ++r) mnew[r] = m_run[r];
        #pragma unroll
        for (int g = 0; g < 4; ++g)
            #pragma unroll
            for (int r = 0; r < 4; ++r) {
                float sv = sacc[g][r] * scale;
                int qi = q0w + hi*4 + r;
                int ki = k0 + g*16 + la;
                sv = (ki <= qi) ? sv : -1e30f;
                sacc[g][r] = sv;
                mnew[r] = fmaxf(mnew[r], sv);
            }
        #pragma unroll
        for (int r = 0; r < 4; ++r) {
            float v = mnew[r];
            v = fmaxf(v, __shfl_xor(v, 1));
            v = fmaxf(v, __shfl_xor(v, 2));
            v = fmaxf(v, __shfl_xor(v, 4));
            v = fmaxf(v, __shfl_xor(v, 8));
            mnew[r] = v;
        }
        float resc[4], lsum[4];
        #pragma unroll
        for (int r = 0; r < 4; ++r) {
            resc[r] = __expf(m_run[r] - mnew[r]);
            m_run[r] = mnew[r];
            lsum[r] = 0.f;
        }
        #pragma unroll
        for (int g = 0; g < 4; ++g)
            #pragma unroll
            for (int r = 0; r < 4; ++r) {
                float p = __expf(sacc[g][r] - mnew[r]);
                sacc[g][r] = p;
                lsum[r] += p;
            }
        #pragma unroll
        for (int r = 0; r < 4; ++r) {
            float v = lsum[r];
            v += __shfl_xor(v, 1); v += __shfl_xor(v, 2);
            v += __shfl_xor(v, 4); v += __shfl_xor(v, 8);
            l_run[r] = l_run[r] * resc[r] + v;
        }
        #pragma unroll
        for (int g = 0; g < 4; ++g)
            #pragma unroll
            for (int r = 0; r < 4; ++r) {
                int prow = hi*4 + r;
                int pcol = (g*16 + la) ^ ((prow & 7) << 3);
                Ps[wid][prow][pcol] = (bf16)sacc[g][r];
            }
        #pragma unroll
        for (int n = 0; n < 8; ++n)
            #pragma unroll
            for (int r = 0; r < 4; ++r) acc_o[n][r] *= resc[r];
        __builtin_amdgcn_s_setprio(1);
        #pragma unroll
        for (int kk = 0; kk < 2; ++kk) {
            bf16x8 pf = *(const bf16x8*)((const char*)&Ps[wid][0][0] + la*128 +
                                         (((kk*32 + hi*8) ^ ((la & 7) << 3)) << 1));
            #pragma unroll
            for (int n = 0; n < 8; ++n) {
                const int vrow = n*16 + la;
                bf16x8 vf = *(const bf16x8*)((const char*)Vts + vrow*128 + (((kk*4 + hi) ^ (la & 7)) << 4));
                acc_o[n] = __builtin_amdgcn_mfma_f32_16x16x32_bf16(pf, vf, acc_o[n], 0, 0, 0);
            }
        }
        __builtin_amdgcn_s_setprio(0);
    }

    bf16* Op = O + (size_t)b * SEQ * DH + (size_t)hh * DQ;
    #pragma unroll
    for (int r = 0; r < 4; ++r) {
        int qi = q0w + hi*4 + r;
        float invl = 1.0f / l_run[r];
        #pragma unroll
        for (int n = 0; n < 8; ++n)
            Op[(size_t)qi * DH + n*16 + la] = (bf16)(acc_o[n][r] * invl);
    }
}

// ---------------- launch ----------------
extern "C" void kernel_launch(void* const* d_in, const int* in_sizes, int n_in,
                              void* d_out, int out_size, void* d_ws, size_t ws_size,
                              hipStream_t stream) {
    const float* x       = (const float*)d_in[0];
    const float* g       = (const float*)d_in[1];
    const float* W_dense = (const float*)d_in[2];
    const float* b_dense = (const float*)d_in[3];
    const float* W_attn  = (const float*)d_in[4];
    const float* W_ffn   = (const float*)d_in[5];
    float* out = (float*)d_out;

    char* ws = (char*)d_ws;
    bf16* normed  = (bf16*)(ws + 0);                    // 16.8 MB (reused as attn_buf)
    bf16* Wd_b    = (bf16*)(ws + 16777216);             // 92.3 MB (reused as q/k/vt)
    bf16* Wa_b    = (bf16*)(ws + 109051904);            // 8.4 MB
    bf16* Wf_b    = (bf16*)(ws + 117440512);            // 33.6 MB
    bf16* h_b     = (bf16*)(ws + 150994944);            // 184.5 MB
    bf16* ag_b    = (bf16*)(ws + 335544320);            // 67.1 MB
    float* ctab   = (float*)(ws + 402653184);           // 0.5 MB
    float* stab   = (float*)(ws + 403177472);           // 0.5 MB
    bf16* q_b  = (bf16*)(ws + 16777216);
    bf16* k_b  = (bf16*)(ws + 16777216 + 16777216);
    bf16* vt_b = (bf16*)(ws + 16777216 + 33554432);
    bf16* attn_b = normed;

    cvt_f32_bf16<<<46137344/2048, 256, 0, stream>>>(W_dense, Wd_b);
    cvt_f32_bf16<<<4194304/2048, 256, 0, stream>>>(W_attn, Wa_b);
    cvt_f32_bf16<<<16777216/2048, 256, 0, stream>>>(W_ffn, Wf_b);
    rmsnorm_k<<<NROWS, 256, 0, stream>>>(x, g, normed);
    // dense GEMM -> h (bf16, +bias): 256^2 fine-phase kernel
    {
        dim3 grid((NROWS/256) * (DOUT/256));            // 16*88 = 1408, %8==0
        gemm256f<0><<<grid, 512, 0, stream>>>(normed, Wd_b, NROWS, DOUT, D_MODEL,
                                              DOUT/256, b_dense, h_b, nullptr, nullptr);
    }
    rope_table<<<SEQ*64/256, 256, 0, stream>>>(ctab, stab);
    rope_qk<<<4194304/256, 256, 0, stream>>>(h_b, ctab, stab, q_b, k_b);
    {
        dim3 grid(SEQ/64, BATCH*NH);
        v_transpose<<<grid, 256, 0, stream>>>(h_b, vt_b);
    }
    silu_k<<<(size_t)NROWS*DFFN/8/256, 256, 0, stream>>>(h_b, ag_b);
    {
        dim3 grid(SEQ/64, BATCH*NH);
        attn_fa<<<grid, 256, 0, stream>>>(q_b, k_b, vt_b, attn_b);
    }
    {
        dim3 grid(D_MODEL/128, NROWS/128);
        gemm_bt<1><<<grid, 256, 0, stream>>>(attn_b, Wa_b, NROWS, D_MODEL, DH,
                                             nullptr, nullptr, x, out);
    }
    {
        dim3 grid(D_MODEL/128, NROWS/128);
        gemm_bt<1><<<grid, 256, 0, stream>>>(ag_b, Wf_b, NROWS, D_MODEL, DFFN,
                                             nullptr, nullptr, out, out);
    }
}

// Round 5
// 845.865 us; speedup vs baseline: 1.1673x; 1.1264x over previous
//
#include <hip/hip_runtime.h>
#include <hip/hip_bf16.h>
#include <cmath>

typedef __bf16 bf16;
typedef __attribute__((ext_vector_type(8))) __bf16 bf16x8;
typedef __attribute__((ext_vector_type(4))) float f32x4;
typedef unsigned int u32;
typedef unsigned short u16;

#define D_MODEL 2048
#define NH 16
#define DQ 128
#define DH 2048
#define DFFN 8192
#define DOUT 22528
#define BATCH 2
#define SEQ 2048
#define NROWS 4096

__device__ __forceinline__ void gload16(const void* g, void* l) {
    __builtin_amdgcn_global_load_lds((__attribute__((address_space(1))) const void*)g,
                                     (__attribute__((address_space(3))) void*)l, 16, 0, 0);
}

__device__ __forceinline__ float bf2f(u16 u) {
    union { u32 i; float f; } c; c.i = ((u32)u) << 16; return c.f;
}

#define VMW(n)  asm volatile("s_waitcnt vmcnt(" #n ")" ::: "memory")
#define LGK0()  asm volatile("s_waitcnt lgkmcnt(0)" ::: "memory")
#define BARX()  { asm volatile("" ::: "memory"); __builtin_amdgcn_s_barrier(); asm volatile("" ::: "memory"); }

// ---------------- fp32 -> bf16 conversion ----------------
__global__ __launch_bounds__(256) void cvt_f32_bf16(const float* __restrict__ in,
                                                    bf16* __restrict__ out) {
    size_t i = ((size_t)blockIdx.x * 256 + threadIdx.x) * 8;
    float4 a = *(const float4*)(in + i);
    float4 b = *(const float4*)(in + i + 4);
    bf16x8 o;
    o[0]=(bf16)a.x; o[1]=(bf16)a.y; o[2]=(bf16)a.z; o[3]=(bf16)a.w;
    o[4]=(bf16)b.x; o[5]=(bf16)b.y; o[6]=(bf16)b.z; o[7]=(bf16)b.w;
    *(bf16x8*)(out + i) = o;
}

// ---------------- RMSNorm (fp32 in -> bf16 out) ----------------
__global__ __launch_bounds__(256) void rmsnorm_k(const float* __restrict__ x,
                                                 const float* __restrict__ g,
                                                 bf16* __restrict__ out) {
    __shared__ float red[4];
    const int row = blockIdx.x;
    const int t = threadIdx.x;
    const float* xr = x + (size_t)row * D_MODEL;
    float4 v0 = *(const float4*)(xr + t*8);
    float4 v1 = *(const float4*)(xr + t*8 + 4);
    float ss = v0.x*v0.x + v0.y*v0.y + v0.z*v0.z + v0.w*v0.w
             + v1.x*v1.x + v1.y*v1.y + v1.z*v1.z + v1.w*v1.w;
    #pragma unroll
    for (int m = 32; m >= 1; m >>= 1) ss += __shfl_xor(ss, m);
    if ((t & 63) == 0) red[t >> 6] = ss;
    __syncthreads();
    float tot = red[0] + red[1] + red[2] + red[3];
    float norm = sqrtf(tot) * 0.022097086912079608f;   // * D^-0.5
    float inv = 1.0f / fmaxf(norm, 1e-8f);
    float4 g0 = *(const float4*)(g + t*8);
    float4 g1 = *(const float4*)(g + t*8 + 4);
    bf16x8 o;
    o[0]=(bf16)(v0.x*inv*g0.x); o[1]=(bf16)(v0.y*inv*g0.y);
    o[2]=(bf16)(v0.z*inv*g0.z); o[3]=(bf16)(v0.w*inv*g0.w);
    o[4]=(bf16)(v1.x*inv*g1.x); o[5]=(bf16)(v1.y*inv*g1.y);
    o[6]=(bf16)(v1.z*inv*g1.z); o[7]=(bf16)(v1.w*inv*g1.w);
    *(bf16x8*)(out + (size_t)row * D_MODEL + t*8) = o;
}

// ============ 256x256 fine-phase BT GEMM (dense QKV+FFN-in) ============
#define SLINE_A(c_, t_) \
    gload16(Asrc + (size_t)((c_)*64)*K + (size_t)(t_)*64, \
            smem + (((t_)&1)<<16) + (c_)*8192 + wid*1024);
#define SLINE_B(c_, t_) \
    gload16(Bsrc + (size_t)((c_)*64)*K + (size_t)(t_)*64, \
            smem + (((t_)&1)<<16) + 32768 + (c_)*8192 + wid*1024);

#define PH_READS_B() \
    _Pragma("unroll") for (int n = 0; n < 4; ++n) { \
        const char* p_ = bb + (wn*64 + n*16 + la) * 128; \
        bfr[n][0] = *(const bf16x8*)(p_ + pg0); \
        bfr[n][1] = *(const bf16x8*)(p_ + pg1); }

#define PH_READS_A(qd_) \
    _Pragma("unroll") for (int mm = 0; mm < 2; ++mm) { \
        const char* p_ = ab + (wm*128 + ((qd_)*2 + mm)*16 + la) * 128; \
        af[mm][0] = *(const bf16x8*)(p_ + pg0); \
        af[mm][1] = *(const bf16x8*)(p_ + pg1); }

#define PH_MFMA(qd_) \
    __builtin_amdgcn_s_setprio(1); \
    _Pragma("unroll") for (int mm = 0; mm < 2; ++mm) \
        _Pragma("unroll") for (int n = 0; n < 4; ++n) { \
            acc[(qd_)*2+mm][n] = __builtin_amdgcn_mfma_f32_16x16x32_bf16(af[mm][0], bfr[n][0], acc[(qd_)*2+mm][n], 0, 0, 0); \
            acc[(qd_)*2+mm][n] = __builtin_amdgcn_mfma_f32_16x16x32_bf16(af[mm][1], bfr[n][1], acc[(qd_)*2+mm][n], 0, 0, 0); } \
    __builtin_amdgcn_s_setprio(0);

template<int MODE>
__global__ __launch_bounds__(512, 2) void gemm256f(
    const bf16* __restrict__ A, const bf16* __restrict__ B,
    int M, int N, int K, int nbx,
    const float* __restrict__ bias, bf16* __restrict__ outb,
    const float* __restrict__ addsrc, float* __restrict__ outf)
{
    __shared__ char smem[131072];          // 2 buf x [A 32KB | B 32KB]
    const int tid = threadIdx.x;
    const int wid = tid >> 6, lane = tid & 63;
    const int la = lane & 15, hi = lane >> 4;
    const int wm = wid >> 2, wn = wid & 3;

    const int nwg = gridDim.x;
    const int cpx = nwg >> 3;
    const int bI = blockIdx.x;
    const int wg = (bI & 7) * cpx + (bI >> 3);
    const int bm = wg / nbx, bn = wg % nbx;
    const size_t m0 = (size_t)bm * 256, n0 = (size_t)bn * 256;

    const int lr = lane >> 3, lg = lane & 7;
    const int sg = lg ^ lr;
    const bf16* Asrc = A + (m0 + wid*8 + lr) * (size_t)K + sg*8;
    const bf16* Bsrc = B + (n0 + wid*8 + lr) * (size_t)K + sg*8;

    const int pg0 = (hi ^ (la & 7)) << 4;
    const int pg1 = ((4 + hi) ^ (la & 7)) << 4;

    f32x4 acc[8][4] = {};
    const int NT = K >> 6;

    SLINE_A(0,0); SLINE_A(2,0);
    SLINE_B(0,0); SLINE_B(1,0);
    SLINE_B(2,0); SLINE_B(3,0);
    SLINE_A(1,0); SLINE_A(3,0);
    VMW(2);
    BARX();

    bf16x8 bfr[4][2];
    bf16x8 af[2][2];

    #pragma unroll 1
    for (int t = 0; t < NT - 1; ++t) {
        const char* ab = smem + ((t & 1) << 16);
        const char* bb = ab + 32768;
        const int nx = t + 1;
        PH_READS_B(); PH_READS_A(0);
        SLINE_A(0,nx); SLINE_A(2,nx);
        BARX(); LGK0(); PH_MFMA(0); BARX();
        PH_READS_A(1);
        SLINE_B(0,nx); SLINE_B(1,nx);
        BARX(); LGK0(); PH_MFMA(1); VMW(4); BARX();
        PH_READS_A(2);
        SLINE_B(2,nx); SLINE_B(3,nx);
        BARX(); LGK0(); PH_MFMA(2); BARX();
        PH_READS_A(3);
        SLINE_A(1,nx); SLINE_A(3,nx);
        BARX(); LGK0(); PH_MFMA(3); VMW(2); BARX();
    }
    {
        const int t = NT - 1;
        const char* ab = smem + ((t & 1) << 16);
        const char* bb = ab + 32768;
        PH_READS_B(); PH_READS_A(0);
        BARX(); LGK0(); PH_MFMA(0); BARX();
        PH_READS_A(1);
        BARX(); LGK0(); PH_MFMA(1); VMW(0); BARX();
        PH_READS_A(2);
        BARX(); LGK0(); PH_MFMA(2); BARX();
        PH_READS_A(3);
        BARX(); LGK0(); PH_MFMA(3); BARX();
    }

    #pragma unroll
    for (int mf = 0; mf < 8; ++mf) {
        const size_t row = m0 + wm*128 + mf*16 + hi*4;
        #pragma unroll
        for (int nf = 0; nf < 4; ++nf) {
            const size_t col = n0 + wn*64 + nf*16 + la;
            if (MODE == 0) {
                const float bv = bias[col];
                #pragma unroll
                for (int r = 0; r < 4; ++r)
                    outb[(row + r) * N + col] = (bf16)(acc[mf][nf][r] + bv);
            } else {
                #pragma unroll
                for (int r = 0; r < 4; ++r) {
                    const size_t off = (row + r) * N + col;
                    outf[off] = addsrc[off] + acc[mf][nf][r];
                }
            }
        }
    }
}

// ============ fused epilogue GEMM: out = x + attn.Wa^T + ag.Wf^T ============
// concat-K (2048 + 8192), BM=128 BN=256, 8 waves (2Mx4N, 64x64/wave),
// 3-buffer LDS (144KB), lead-2-tile staging, vmcnt(6) once per tile.
#define OSTAGE_A(st_, c_) { \
    const bf16* s_ = (st_) < 32 ? A1s + (size_t)((c_)*64)*2048 + (size_t)(st_)*64 \
                                : A2s + (size_t)((c_)*64)*8192 + (size_t)((st_)-32)*64; \
    gload16(s_, smem + ((st_)%3)*49152 + (c_)*8192 + wid*1024); }
#define OSTAGE_B(st_, c_) { \
    const bf16* s_ = (st_) < 32 ? B1s + (size_t)((c_)*64)*2048 + (size_t)(st_)*64 \
                                : B2s + (size_t)((c_)*64)*8192 + (size_t)((st_)-32)*64; \
    gload16(s_, smem + ((st_)%3)*49152 + 16384 + (c_)*8192 + wid*1024); }

__global__ __launch_bounds__(512, 2) void gemm_out(
    const bf16* __restrict__ A1, const bf16* __restrict__ B1,   // attn [4096,2048], Wa [2048,2048]
    const bf16* __restrict__ A2, const bf16* __restrict__ B2,   // ag [4096,8192],  Wf [2048,8192]
    const float* __restrict__ x, float* __restrict__ outf)
{
    __shared__ char smem[147456];     // 3 bufs x [A 16KB | B 32KB]
    const int tid = threadIdx.x;
    const int wid = tid >> 6, lane = tid & 63;
    const int la = lane & 15, hi = lane >> 4;
    const int wm = wid >> 2, wn = wid & 3;     // 2 x 4 waves

    const int nwg = gridDim.x;                 // 256
    const int cpx = nwg >> 3;
    const int bI = blockIdx.x;
    const int wg = (bI & 7) * cpx + (bI >> 3);
    const int bm = wg >> 3, bn = wg & 7;       // 32 x 8 blocks
    const size_t m0 = (size_t)bm * 128, n0 = (size_t)bn * 256;

    const int lr = lane >> 3, lg = lane & 7;
    const int sg = lg ^ lr;
    const bf16* A1s = A1 + (m0 + wid*8 + lr) * (size_t)2048 + sg*8;
    const bf16* A2s = A2 + (m0 + wid*8 + lr) * (size_t)8192 + sg*8;
    const bf16* B1s = B1 + (n0 + wid*8 + lr) * (size_t)2048 + sg*8;
    const bf16* B2s = B2 + (n0 + wid*8 + lr) * (size_t)8192 + sg*8;

    const int pg0 = (hi ^ (la & 7)) << 4;
    const int pg1 = ((4 + hi) ^ (la & 7)) << 4;

    f32x4 acc[4][4] = {};
    const int NT = 160;                        // 32 (attn) + 128 (ffn)

    // prologue: stage tiles 0 and 1 (6 lines each); tile 0 landed
    OSTAGE_A(0,0); OSTAGE_A(0,1);
    OSTAGE_B(0,0); OSTAGE_B(0,1); OSTAGE_B(0,2); OSTAGE_B(0,3);
    OSTAGE_A(1,0); OSTAGE_A(1,1);
    OSTAGE_B(1,0); OSTAGE_B(1,1); OSTAGE_B(1,2); OSTAGE_B(1,3);
    VMW(6);
    BARX();

    bf16x8 af[4], bfr[4];
    #pragma unroll 1
    for (int t = 0; t < NT; ++t) {
        const char* ab = smem + (t % 3) * 49152;
        const char* bb = ab + 16384;
        const int st = t + 2;
        // phase 0 (kk0)
        #pragma unroll
        for (int m = 0; m < 4; ++m) af[m]  = *(const bf16x8*)(ab + (wm*64 + m*16 + la)*128 + pg0);
        #pragma unroll
        for (int n = 0; n < 4; ++n) bfr[n] = *(const bf16x8*)(bb + (wn*64 + n*16 + la)*128 + pg0);
        if (st < NT) { OSTAGE_A(st,0); OSTAGE_A(st,1); OSTAGE_B(st,0); }
        BARX(); LGK0();
        __builtin_amdgcn_s_setprio(1);
        #pragma unroll
        for (int m = 0; m < 4; ++m)
            #pragma unroll
            for (int n = 0; n < 4; ++n)
                acc[m][n] = __builtin_amdgcn_mfma_f32_16x16x32_bf16(af[m], bfr[n], acc[m][n], 0, 0, 0);
        __builtin_amdgcn_s_setprio(0);
        BARX();
        // phase 1 (kk1)
        #pragma unroll
        for (int m = 0; m < 4; ++m) af[m]  = *(const bf16x8*)(ab + (wm*64 + m*16 + la)*128 + pg1);
        #pragma unroll
        for (int n = 0; n < 4; ++n) bfr[n] = *(const bf16x8*)(bb + (wn*64 + n*16 + la)*128 + pg1);
        if (st < NT) { OSTAGE_B(st,1); OSTAGE_B(st,2); OSTAGE_B(st,3); }
        if (t < NT - 2) { VMW(6); } else { VMW(0); }
        BARX(); LGK0();
        __builtin_amdgcn_s_setprio(1);
        #pragma unroll
        for (int m = 0; m < 4; ++m)
            #pragma unroll
            for (int n = 0; n < 4; ++n)
                acc[m][n] = __builtin_amdgcn_mfma_f32_16x16x32_bf16(af[m], bfr[n], acc[m][n], 0, 0, 0);
        __builtin_amdgcn_s_setprio(0);
        BARX();
    }

    #pragma unroll
    for (int mf = 0; mf < 4; ++mf) {
        const size_t row = m0 + wm*64 + mf*16 + hi*4;
        #pragma unroll
        for (int nf = 0; nf < 4; ++nf) {
            const size_t col = n0 + wn*64 + nf*16 + la;
            #pragma unroll
            for (int r = 0; r < 4; ++r) {
                const size_t off = (row + r) * (size_t)DH + col;
                outf[off] = x[off] + acc[mf][nf][r];
            }
        }
    }
}

// ---------------- RoPE table ----------------
__global__ __launch_bounds__(256) void rope_table(float* __restrict__ ctab,
                                                  float* __restrict__ stab) {
    int idx = blockIdx.x * 256 + threadIdx.x;     // l*64 + i
    int l = idx >> 6, i = idx & 63;
    float inv = powf(10000.0f, -(float)i / 64.0f);
    float ang = (float)l * inv;
    float s, c;
    sincosf(ang, &s, &c);
    ctab[idx] = c; stab[idx] = s;
}

__device__ __forceinline__ u32 rope_pair(u32 u, float c, float s) {
    float t1 = bf2f((u16)(u & 0xffff));
    float t2 = bf2f((u16)(u >> 16));
    float r1 = t1 * c - t2 * s;
    float r2 = t1 * s + t2 * c;
    bf16 b1 = (bf16)r1, b2 = (bf16)r2;
    return (u32)__builtin_bit_cast(u16, b1) | ((u32)__builtin_bit_cast(u16, b2) << 16);
}

// ---------------- q/k rope + reshape to [B,H,L,128] ----------------
__global__ __launch_bounds__(256) void rope_qk(const bf16* __restrict__ h,
                                               const float* __restrict__ ctab,
                                               const float* __restrict__ stab,
                                               bf16* __restrict__ qb, bf16* __restrict__ kb) {
    int idx = blockIdx.x * 256 + threadIdx.x;
    int i  = idx & 63;
    int hh = (idx >> 6) & 15;
    int l  = (idx >> 10) & 2047;
    int b  = idx >> 21;
    size_t hrow = (size_t)(b * SEQ + l) * DOUT;
    float c = ctab[l*64 + i], s = stab[l*64 + i];
    u32 uq = *(const u32*)(h + hrow + hh*DQ + 2*i);
    u32 uk = *(const u32*)(h + hrow + DH + hh*DQ + 2*i);
    size_t orow = ((size_t)(b*NH + hh) * SEQ + l) * DQ + 2*i;
    *(u32*)(qb + orow) = rope_pair(uq, c, s);
    *(u32*)(kb + orow) = rope_pair(uk, c, s);
}

// ---------------- V transpose: h_bf16 v-section -> vt [B,H,128,L] ----------------
__global__ __launch_bounds__(256) void v_transpose(const bf16* __restrict__ h,
                                                   bf16* __restrict__ vt) {
    __shared__ u32 lds[64][68];
    const int lt = blockIdx.x, bh = blockIdx.y;
    const int b = bh >> 4, hh = bh & 15;
    const int t = threadIdx.x;
    const bf16* src = h + (size_t)(b * SEQ + lt * 64) * DOUT + 2*DH + hh * DQ;
    #pragma unroll
    for (int i = 0; i < 4; ++i) {
        int j = i*256 + t;
        int l = j >> 4, ch = j & 15;
        uint4 v = *(const uint4*)(src + (size_t)l * DOUT + ch*8);
        *(uint4*)&lds[l][ch*4] = v;
    }
    __syncthreads();
    bf16* dst = vt + (size_t)bh * DQ * SEQ + lt * 64;
    #pragma unroll
    for (int i = 0; i < 4; ++i) {
        int j = i*256 + t;
        int d = j >> 3, lc = j & 7;
        u32 out[4];
        #pragma unroll
        for (int m = 0; m < 4; ++m) {
            u32 a0 = lds[lc*8 + 2*m][d >> 1];
            u32 a1 = lds[lc*8 + 2*m + 1][d >> 1];
            u16 s0 = (d & 1) ? (u16)(a0 >> 16) : (u16)(a0 & 0xffff);
            u16 s1 = (d & 1) ? (u16)(a1 >> 16) : (u16)(a1 & 0xffff);
            out[m] = (u32)s0 | ((u32)s1 << 16);
        }
        *(uint4*)(dst + (size_t)d * SEQ + lc*8) = *(uint4*)out;
    }
}

// ---------------- SwiGLU: ag = a * silu(b) ----------------
__global__ __launch_bounds__(256) void silu_k(const bf16* __restrict__ h,
                                              bf16* __restrict__ ag) {
    size_t idx = ((size_t)blockIdx.x * 256 + threadIdx.x) * 8;
    int r = (int)(idx >> 13);
    int f = (int)(idx & 8191);
    const bf16* hr = h + (size_t)r * DOUT + 3*DH;
    bf16x8 va = *(const bf16x8*)(hr + f);
    bf16x8 vb = *(const bf16x8*)(hr + DFFN + f);
    bf16x8 o;
    #pragma unroll
    for (int j = 0; j < 8; ++j) {
        float a = (float)va[j];
        float b = (float)vb[j];
        float sil = b / (1.0f + __expf(-b));
        o[j] = (bf16)(a * sil);
    }
    *(bf16x8*)(ag + idx) = o;
}

// ---------------- causal flash attention ----------------
__global__ __launch_bounds__(256) void attn_fa(const bf16* __restrict__ Q,
                                               const bf16* __restrict__ Kb,
                                               const bf16* __restrict__ Vt,
                                               bf16* __restrict__ O) {
    __shared__ bf16 Ks[64][128];
    __shared__ bf16 Vts[128][64];
    __shared__ bf16 Ps[4][16][64];
    const int qt = blockIdx.x, bh = blockIdx.y;
    const int b = bh >> 4, hh = bh & 15;
    const int tid = threadIdx.x, wid = tid >> 6, lane = tid & 63;
    const int la = lane & 15, hi = lane >> 4;
    const bf16* Qp = Q + (size_t)bh * SEQ * DQ;
    const bf16* Kp = Kb + (size_t)bh * SEQ * DQ;
    const bf16* Vp = Vt + (size_t)bh * DQ * SEQ;
    const int q0w = qt * 64 + wid * 16;

    bf16x8 qf[4];
    #pragma unroll
    for (int s = 0; s < 4; ++s)
        qf[s] = *(const bf16x8*)(Qp + (size_t)(q0w + la) * DQ + s*32 + hi*8);

    f32x4 acc_o[8] = {};
    float m_run[4] = {-1e30f, -1e30f, -1e30f, -1e30f};
    float l_run[4] = {0.f, 0.f, 0.f, 0.f};
    const float scale = 0.08838834764831845f;

    const int nk = qt + 1;
    for (int kt = 0; kt < nk; ++kt) {
        const int k0 = kt * 64;
        __syncthreads();
        #pragma unroll
        for (int i = 0; i < 4; ++i) {
            int j = i*256 + tid;
            int kr = j >> 4, jg = j & 15;
            gload16(Kp + (size_t)(k0 + kr) * DQ + ((jg ^ (kr & 7)) << 3),
                    (char*)Ks + i*4096 + wid*1024);
            int d = j >> 3, vg = j & 7;
            gload16(Vp + (size_t)d * SEQ + k0 + ((vg ^ (d & 7)) << 3),
                    (char*)Vts + i*4096 + wid*1024);
        }
        __syncthreads();

        f32x4 sacc[4] = {};
        __builtin_amdgcn_s_setprio(1);
        #pragma unroll
        for (int g = 0; g < 4; ++g) {
            const int krow = g*16 + la;
            #pragma unroll
            for (int s = 0; s < 4; ++s) {
                bf16x8 kf = *(const bf16x8*)((const char*)Ks + krow*256 + (((s*4 + hi) ^ (la & 7)) << 4));
                sacc[g] = __builtin_amdgcn_mfma_f32_16x16x32_bf16(qf[s], kf, sacc[g], 0, 0, 0);
            }
        }
        __builtin_amdgcn_s_setprio(0);

        float mnew[4];
        #pragma unroll
        for (int r = 0; r < 4; ++r) mnew[r] = m_run[r];
        #pragma unroll
        for (int g = 0; g < 4; ++g)
            #pragma unroll
            for (int r = 0; r < 4; ++r) {
                float sv = sacc[g][r] * scale;
                int qi = q0w + hi*4 + r;
                int ki = k0 + g*16 + la;
                sv = (ki <= qi) ? sv : -1e30f;
                sacc[g][r] = sv;
                mnew[r] = fmaxf(mnew[r], sv);
            }
        #pragma unroll
        for (int r = 0; r < 4; ++r) {
            float v = mnew[r];
            v = fmaxf(v, __shfl_xor(v, 1));
            v = fmaxf(v, __shfl_xor(v, 2));
            v = fmaxf(v, __shfl_xor(v, 4));
            v = fmaxf(v, __shfl_xor(v, 8));
            mnew[r] = v;
        }
        float resc[4], lsum[4];
        #pragma unroll
        for (int r = 0; r < 4; ++r) {
            resc[r] = __expf(m_run[r] - mnew[r]);
            m_run[r] = mnew[r];
            lsum[r] = 0.f;
        }
        #pragma unroll
        for (int g = 0; g < 4; ++g)
            #pragma unroll
            for (int r = 0; r < 4; ++r) {
                float p = __expf(sacc[g][r] - mnew[r]);
                sacc[g][r] = p;
                lsum[r] += p;
            }
        #pragma unroll
        for (int r = 0; r < 4; ++r) {
            float v = lsum[r];
            v += __shfl_xor(v, 1); v += __shfl_xor(v, 2);
            v += __shfl_xor(v, 4); v += __shfl_xor(v, 8);
            l_run[r] = l_run[r] * resc[r] + v;
        }
        #pragma unroll
        for (int g = 0; g < 4; ++g)
            #pragma unroll
            for (int r = 0; r < 4; ++r) {
                int prow = hi*4 + r;
                int pcol = (g*16 + la) ^ ((prow & 7) << 3);
                Ps[wid][prow][pcol] = (bf16)sacc[g][r];
            }
        #pragma unroll
        for (int n = 0; n < 8; ++n)
            #pragma unroll
            for (int r = 0; r < 4; ++r) acc_o[n][r] *= resc[r];
        __builtin_amdgcn_s_setprio(1);
        #pragma unroll
        for (int kk = 0; kk < 2; ++kk) {
            bf16x8 pf = *(const bf16x8*)((const char*)&Ps[wid][0][0] + la*128 +
                                         (((kk*32 + hi*8) ^ ((la & 7) << 3)) << 1));
            #pragma unroll
            for (int n = 0; n < 8; ++n) {
                const int vrow = n*16 + la;
                bf16x8 vf = *(const bf16x8*)((const char*)Vts + vrow*128 + (((kk*4 + hi) ^ (la & 7)) << 4));
                acc_o[n] = __builtin_amdgcn_mfma_f32_16x16x32_bf16(pf, vf, acc_o[n], 0, 0, 0);
            }
        }
        __builtin_amdgcn_s_setprio(0);
    }

    bf16* Op = O + (size_t)b * SEQ * DH + (size_t)hh * DQ;
    #pragma unroll
    for (int r = 0; r < 4; ++r) {
        int qi = q0w + hi*4 + r;
        float invl = 1.0f / l_run[r];
        #pragma unroll
        for (int n = 0; n < 8; ++n)
            Op[(size_t)qi * DH + n*16 + la] = (bf16)(acc_o[n][r] * invl);
    }
}

// ---------------- launch ----------------
extern "C" void kernel_launch(void* const* d_in, const int* in_sizes, int n_in,
                              void* d_out, int out_size, void* d_ws, size_t ws_size,
                              hipStream_t stream) {
    const float* x       = (const float*)d_in[0];
    const float* g       = (const float*)d_in[1];
    const float* W_dense = (const float*)d_in[2];
    const float* b_dense = (const float*)d_in[3];
    const float* W_attn  = (const float*)d_in[4];
    const float* W_ffn   = (const float*)d_in[5];
    float* out = (float*)d_out;

    char* ws = (char*)d_ws;
    bf16* normed  = (bf16*)(ws + 0);                    // 16.8 MB (reused as attn_buf)
    bf16* Wd_b    = (bf16*)(ws + 16777216);             // 92.3 MB (reused as q/k/vt)
    bf16* Wa_b    = (bf16*)(ws + 109051904);            // 8.4 MB
    bf16* Wf_b    = (bf16*)(ws + 117440512);            // 33.6 MB
    bf16* h_b     = (bf16*)(ws + 150994944);            // 184.5 MB
    bf16* ag_b    = (bf16*)(ws + 335544320);            // 67.1 MB
    float* ctab   = (float*)(ws + 402653184);           // 0.5 MB
    float* stab   = (float*)(ws + 403177472);           // 0.5 MB
    bf16* q_b  = (bf16*)(ws + 16777216);
    bf16* k_b  = (bf16*)(ws + 16777216 + 16777216);
    bf16* vt_b = (bf16*)(ws + 16777216 + 33554432);
    bf16* attn_b = normed;

    cvt_f32_bf16<<<46137344/2048, 256, 0, stream>>>(W_dense, Wd_b);
    cvt_f32_bf16<<<4194304/2048, 256, 0, stream>>>(W_attn, Wa_b);
    cvt_f32_bf16<<<16777216/2048, 256, 0, stream>>>(W_ffn, Wf_b);
    rmsnorm_k<<<NROWS, 256, 0, stream>>>(x, g, normed);
    {
        dim3 grid((NROWS/256) * (DOUT/256));            // 1408, %8==0
        gemm256f<0><<<grid, 512, 0, stream>>>(normed, Wd_b, NROWS, DOUT, D_MODEL,
                                              DOUT/256, b_dense, h_b, nullptr, nullptr);
    }
    rope_table<<<SEQ*64/256, 256, 0, stream>>>(ctab, stab);
    rope_qk<<<4194304/256, 256, 0, stream>>>(h_b, ctab, stab, q_b, k_b);
    {
        dim3 grid(SEQ/64, BATCH*NH);
        v_transpose<<<grid, 256, 0, stream>>>(h_b, vt_b);
    }
    silu_k<<<(size_t)NROWS*DFFN/8/256, 256, 0, stream>>>(h_b, ag_b);
    {
        dim3 grid(SEQ/64, BATCH*NH);
        attn_fa<<<grid, 256, 0, stream>>>(q_b, k_b, vt_b, attn_b);
    }
    // fused: out = x + attn.Wa^T + ag.Wf^T  (concat-K, full-GPU grid)
    gemm_out<<<256, 512, 0, stream>>>(attn_b, Wa_b, ag_b, Wf_b, x, out);
}

// Round 6
// 819.897 us; speedup vs baseline: 1.2043x; 1.0317x over previous
//
#include <hip/hip_runtime.h>
#include <hip/hip_bf16.h>
#include <cmath>

typedef __bf16 bf16;
typedef __attribute__((ext_vector_type(8))) __bf16 bf16x8;
typedef __attribute__((ext_vector_type(4))) float f32x4;
typedef unsigned int u32;
typedef unsigned short u16;

#define D_MODEL 2048
#define NH 16
#define DQ 128
#define DH 2048
#define DFFN 8192
#define DOUT 22528
#define HQKV 6144
#define BATCH 2
#define SEQ 2048
#define NROWS 4096

__device__ __forceinline__ void gload16(const void* g, void* l) {
    __builtin_amdgcn_global_load_lds((__attribute__((address_space(1))) const void*)g,
                                     (__attribute__((address_space(3))) void*)l, 16, 0, 0);
}

__device__ __forceinline__ float bf2f(u16 u) {
    union { u32 i; float f; } c; c.i = ((u32)u) << 16; return c.f;
}

#define VMW(n)  asm volatile("s_waitcnt vmcnt(" #n ")" ::: "memory")
#define LGK0()  asm volatile("s_waitcnt lgkmcnt(0)" ::: "memory")
#define BARX()  { asm volatile("" ::: "memory"); __builtin_amdgcn_s_barrier(); asm volatile("" ::: "memory"); }

// ---------------- fp32 -> bf16 conversion (plain) ----------------
__global__ __launch_bounds__(256) void cvt_f32_bf16(const float* __restrict__ in,
                                                    bf16* __restrict__ out) {
    size_t i = ((size_t)blockIdx.x * 256 + threadIdx.x) * 8;
    float4 a = *(const float4*)(in + i);
    float4 b = *(const float4*)(in + i + 4);
    bf16x8 o;
    o[0]=(bf16)a.x; o[1]=(bf16)a.y; o[2]=(bf16)a.z; o[3]=(bf16)a.w;
    o[4]=(bf16)b.x; o[5]=(bf16)b.y; o[6]=(bf16)b.z; o[7]=(bf16)b.w;
    *(bf16x8*)(out + i) = o;
}

// ---------------- W_dense conversion with gate-interleave row remap ----------------
// new row nr: nr<6144 -> orig nr (qkv).  Else g=nr-6144, blk=g>>4,
// f=(blk>>1)*16+(g&15); orig = blk odd ? 14336+f (b/gate) : 6144+f (a).
__global__ __launch_bounds__(256) void cvt_wd(const float* __restrict__ in,
                                              bf16* __restrict__ out) {
    size_t i = ((size_t)blockIdx.x * 256 + threadIdx.x) * 8;
    int nr = (int)(i >> 11);
    int c  = (int)(i & 2047);
    int orig;
    if (nr < HQKV) orig = nr;
    else {
        int gg = nr - HQKV;
        int blk = gg >> 4;
        int f = ((blk >> 1) << 4) + (gg & 15);
        orig = (blk & 1) ? (3*DH + DFFN + f) : (3*DH + f);
    }
    const float* src = in + (size_t)orig * 2048 + c;
    float4 a = *(const float4*)src;
    float4 b = *(const float4*)(src + 4);
    bf16x8 o;
    o[0]=(bf16)a.x; o[1]=(bf16)a.y; o[2]=(bf16)a.z; o[3]=(bf16)a.w;
    o[4]=(bf16)b.x; o[5]=(bf16)b.y; o[6]=(bf16)b.z; o[7]=(bf16)b.w;
    *(bf16x8*)(out + i) = o;
}

// ---------------- RMSNorm (fp32 in -> bf16 out) ----------------
__global__ __launch_bounds__(256) void rmsnorm_k(const float* __restrict__ x,
                                                 const float* __restrict__ g,
                                                 bf16* __restrict__ out) {
    __shared__ float red[4];
    const int row = blockIdx.x;
    const int t = threadIdx.x;
    const float* xr = x + (size_t)row * D_MODEL;
    float4 v0 = *(const float4*)(xr + t*8);
    float4 v1 = *(const float4*)(xr + t*8 + 4);
    float ss = v0.x*v0.x + v0.y*v0.y + v0.z*v0.z + v0.w*v0.w
             + v1.x*v1.x + v1.y*v1.y + v1.z*v1.z + v1.w*v1.w;
    #pragma unroll
    for (int m = 32; m >= 1; m >>= 1) ss += __shfl_xor(ss, m);
    if ((t & 63) == 0) red[t >> 6] = ss;
    __syncthreads();
    float tot = red[0] + red[1] + red[2] + red[3];
    float norm = sqrtf(tot) * 0.022097086912079608f;
    float inv = 1.0f / fmaxf(norm, 1e-8f);
    float4 g0 = *(const float4*)(g + t*8);
    float4 g1 = *(const float4*)(g + t*8 + 4);
    bf16x8 o;
    o[0]=(bf16)(v0.x*inv*g0.x); o[1]=(bf16)(v0.y*inv*g0.y);
    o[2]=(bf16)(v0.z*inv*g0.z); o[3]=(bf16)(v0.w*inv*g0.w);
    o[4]=(bf16)(v1.x*inv*g1.x); o[5]=(bf16)(v1.y*inv*g1.y);
    o[6]=(bf16)(v1.z*inv*g1.z); o[7]=(bf16)(v1.w*inv*g1.w);
    *(bf16x8*)(out + (size_t)row * D_MODEL + t*8) = o;
}

// ============ 256x256 fine-phase dense GEMM + fused SwiGLU epilogue ============
// bn-major block order (W panel L2-resident per XCD); K=2048.
#define SLINE_A(c_, t_) \
    gload16(Asrc + (size_t)((c_)*64)*2048 + (size_t)(t_)*64, \
            smem + (((t_)&1)<<16) + (c_)*8192 + wid*1024);
#define SLINE_B(c_, t_) \
    gload16(Bsrc + (size_t)((c_)*64)*2048 + (size_t)(t_)*64, \
            smem + (((t_)&1)<<16) + 32768 + (c_)*8192 + wid*1024);

#define PH_READS_B() \
    _Pragma("unroll") for (int n = 0; n < 4; ++n) { \
        const char* p_ = bb + (wn*64 + n*16 + la) * 128; \
        bfr[n][0] = *(const bf16x8*)(p_ + pg0); \
        bfr[n][1] = *(const bf16x8*)(p_ + pg1); }

#define PH_READS_A(qd_) \
    _Pragma("unroll") for (int mm = 0; mm < 2; ++mm) { \
        const char* p_ = ab + (wm*128 + ((qd_)*2 + mm)*16 + la) * 128; \
        af[mm][0] = *(const bf16x8*)(p_ + pg0); \
        af[mm][1] = *(const bf16x8*)(p_ + pg1); }

#define PH_MFMA(qd_) \
    __builtin_amdgcn_s_setprio(1); \
    _Pragma("unroll") for (int mm = 0; mm < 2; ++mm) \
        _Pragma("unroll") for (int n = 0; n < 4; ++n) { \
            acc[(qd_)*2+mm][n] = __builtin_amdgcn_mfma_f32_16x16x32_bf16(af[mm][0], bfr[n][0], acc[(qd_)*2+mm][n], 0, 0, 0); \
            acc[(qd_)*2+mm][n] = __builtin_amdgcn_mfma_f32_16x16x32_bf16(af[mm][1], bfr[n][1], acc[(qd_)*2+mm][n], 0, 0, 0); } \
    __builtin_amdgcn_s_setprio(0);

__global__ __launch_bounds__(512, 2) void gemm_dense(
    const bf16* __restrict__ A, const bf16* __restrict__ B,
    const float* __restrict__ bias, bf16* __restrict__ h6,
    bf16* __restrict__ ag)
{
    __shared__ char smem[131072];
    const int tid = threadIdx.x;
    const int wid = tid >> 6, lane = tid & 63;
    const int la = lane & 15, hi = lane >> 4;
    const int wm = wid >> 2, wn = wid & 3;

    const int nwg = gridDim.x;                 // 1408
    const int cpx = nwg >> 3;                  // 176
    const int bI = blockIdx.x;
    const int wg = (bI & 7) * cpx + (bI >> 3);
    const int bn = wg >> 4, bm = wg & 15;      // bn-major: 16 row-blocks share W panel
    const size_t m0 = (size_t)bm * 256, n0 = (size_t)bn * 256;

    const int lr = lane >> 3, lg = lane & 7;
    const int sg = lg ^ lr;
    const bf16* Asrc = A + (m0 + wid*8 + lr) * (size_t)2048 + sg*8;
    const bf16* Bsrc = B + (n0 + wid*8 + lr) * (size_t)2048 + sg*8;

    const int pg0 = (hi ^ (la & 7)) << 4;
    const int pg1 = ((4 + hi) ^ (la & 7)) << 4;

    f32x4 acc[8][4] = {};
    const int NT = 32;                         // 2048/64

    SLINE_A(0,0); SLINE_A(2,0);
    SLINE_B(0,0); SLINE_B(1,0);
    SLINE_B(2,0); SLINE_B(3,0);
    SLINE_A(1,0); SLINE_A(3,0);
    VMW(2);
    BARX();

    bf16x8 bfr[4][2];
    bf16x8 af[2][2];

    #pragma unroll 1
    for (int t = 0; t < NT - 1; ++t) {
        const char* ab = smem + ((t & 1) << 16);
        const char* bb = ab + 32768;
        const int nx = t + 1;
        PH_READS_B(); PH_READS_A(0);
        SLINE_A(0,nx); SLINE_A(2,nx);
        BARX(); LGK0(); PH_MFMA(0); BARX();
        PH_READS_A(1);
        SLINE_B(0,nx); SLINE_B(1,nx);
        BARX(); LGK0(); PH_MFMA(1); VMW(4); BARX();
        PH_READS_A(2);
        SLINE_B(2,nx); SLINE_B(3,nx);
        BARX(); LGK0(); PH_MFMA(2); BARX();
        PH_READS_A(3);
        SLINE_A(1,nx); SLINE_A(3,nx);
        BARX(); LGK0(); PH_MFMA(3); VMW(2); BARX();
    }
    {
        const int t = NT - 1;
        const char* ab = smem + ((t & 1) << 16);
        const char* bb = ab + 32768;
        PH_READS_B(); PH_READS_A(0);
        BARX(); LGK0(); PH_MFMA(0); BARX();
        PH_READS_A(1);
        BARX(); LGK0(); PH_MFMA(1); VMW(0); BARX();
        PH_READS_A(2);
        BARX(); LGK0(); PH_MFMA(2); BARX();
        PH_READS_A(3);
        BARX(); LGK0(); PH_MFMA(3); BARX();
    }

    if (n0 < HQKV) {
        // qkv region -> h6 [4096, 6144] bf16, +bias
        #pragma unroll
        for (int mf = 0; mf < 8; ++mf) {
            const size_t row = m0 + wm*128 + mf*16 + hi*4;
            #pragma unroll
            for (int nf = 0; nf < 4; ++nf) {
                const size_t col = n0 + wn*64 + nf*16 + la;
                const float bv = bias[col];
                #pragma unroll
                for (int r = 0; r < 4; ++r)
                    h6[(row + r) * HQKV + col] = (bf16)(acc[mf][nf][r] + bv);
            }
        }
    } else {
        // gate region (interleaved a|b 16-col blocks) -> ag [4096, 8192]
        #pragma unroll
        for (int mf = 0; mf < 8; ++mf) {
            const size_t row = m0 + wm*128 + mf*16 + hi*4;
            #pragma unroll
            for (int np = 0; np < 4; np += 2) {
                const int col_a = (int)n0 + wn*64 + np*16 + la;
                const int gg = col_a - HQKV;
                const int f = ((gg >> 5) << 4) + (gg & 15);
                const float ba = bias[3*DH + f];
                const float bb2 = bias[3*DH + DFFN + f];
                #pragma unroll
                for (int r = 0; r < 4; ++r) {
                    float a = acc[mf][np][r] + ba;
                    float b = acc[mf][np+1][r] + bb2;
                    float sil = b / (1.0f + __expf(-b));
                    ag[(row + r) * (size_t)DFFN + f] = (bf16)(a * sil);
                }
            }
        }
    }
}

// ============ fused epilogue GEMM: out = x + attn.Wa^T + ag.Wf^T ============
#define OSTAGE_A(st_, c_) { \
    const bf16* s_ = (st_) < 32 ? A1s + (size_t)((c_)*64)*2048 + (size_t)(st_)*64 \
                                : A2s + (size_t)((c_)*64)*8192 + (size_t)((st_)-32)*64; \
    gload16(s_, smem + ((st_)%3)*49152 + (c_)*8192 + wid*1024); }
#define OSTAGE_B(st_, c_) { \
    const bf16* s_ = (st_) < 32 ? B1s + (size_t)((c_)*64)*2048 + (size_t)(st_)*64 \
                                : B2s + (size_t)((c_)*64)*8192 + (size_t)((st_)-32)*64; \
    gload16(s_, smem + ((st_)%3)*49152 + 16384 + (c_)*8192 + wid*1024); }

__global__ __launch_bounds__(512, 2) void gemm_out(
    const bf16* __restrict__ A1, const bf16* __restrict__ B1,
    const bf16* __restrict__ A2, const bf16* __restrict__ B2,
    const float* __restrict__ x, float* __restrict__ outf)
{
    __shared__ char smem[147456];
    const int tid = threadIdx.x;
    const int wid = tid >> 6, lane = tid & 63;
    const int la = lane & 15, hi = lane >> 4;
    const int wm = wid >> 2, wn = wid & 3;

    const int nwg = gridDim.x;                 // 256
    const int cpx = nwg >> 3;
    const int bI = blockIdx.x;
    const int wg = (bI & 7) * cpx + (bI >> 3);
    const int bm = wg >> 3, bn = wg & 7;
    const size_t m0 = (size_t)bm * 128, n0 = (size_t)bn * 256;

    const int lr = lane >> 3, lg = lane & 7;
    const int sg = lg ^ lr;
    const bf16* A1s = A1 + (m0 + wid*8 + lr) * (size_t)2048 + sg*8;
    const bf16* A2s = A2 + (m0 + wid*8 + lr) * (size_t)8192 + sg*8;
    const bf16* B1s = B1 + (n0 + wid*8 + lr) * (size_t)2048 + sg*8;
    const bf16* B2s = B2 + (n0 + wid*8 + lr) * (size_t)8192 + sg*8;

    const int pg0 = (hi ^ (la & 7)) << 4;
    const int pg1 = ((4 + hi) ^ (la & 7)) << 4;

    f32x4 acc[4][4] = {};
    const int NT = 160;

    OSTAGE_A(0,0); OSTAGE_A(0,1);
    OSTAGE_B(0,0); OSTAGE_B(0,1); OSTAGE_B(0,2); OSTAGE_B(0,3);
    OSTAGE_A(1,0); OSTAGE_A(1,1);
    OSTAGE_B(1,0); OSTAGE_B(1,1); OSTAGE_B(1,2); OSTAGE_B(1,3);
    VMW(6);
    BARX();

    bf16x8 af[4], bfr[4];
    #pragma unroll 1
    for (int t = 0; t < NT; ++t) {
        const char* ab = smem + (t % 3) * 49152;
        const char* bb = ab + 16384;
        const int st = t + 2;
        #pragma unroll
        for (int m = 0; m < 4; ++m) af[m]  = *(const bf16x8*)(ab + (wm*64 + m*16 + la)*128 + pg0);
        #pragma unroll
        for (int n = 0; n < 4; ++n) bfr[n] = *(const bf16x8*)(bb + (wn*64 + n*16 + la)*128 + pg0);
        if (st < NT) { OSTAGE_A(st,0); OSTAGE_A(st,1); OSTAGE_B(st,0); }
        BARX(); LGK0();
        __builtin_amdgcn_s_setprio(1);
        #pragma unroll
        for (int m = 0; m < 4; ++m)
            #pragma unroll
            for (int n = 0; n < 4; ++n)
                acc[m][n] = __builtin_amdgcn_mfma_f32_16x16x32_bf16(af[m], bfr[n], acc[m][n], 0, 0, 0);
        __builtin_amdgcn_s_setprio(0);
        BARX();
        #pragma unroll
        for (int m = 0; m < 4; ++m) af[m]  = *(const bf16x8*)(ab + (wm*64 + m*16 + la)*128 + pg1);
        #pragma unroll
        for (int n = 0; n < 4; ++n) bfr[n] = *(const bf16x8*)(bb + (wn*64 + n*16 + la)*128 + pg1);
        if (st < NT) { OSTAGE_B(st,1); OSTAGE_B(st,2); OSTAGE_B(st,3); }
        if (t < NT - 2) { VMW(6); } else { VMW(0); }
        BARX(); LGK0();
        __builtin_amdgcn_s_setprio(1);
        #pragma unroll
        for (int m = 0; m < 4; ++m)
            #pragma unroll
            for (int n = 0; n < 4; ++n)
                acc[m][n] = __builtin_amdgcn_mfma_f32_16x16x32_bf16(af[m], bfr[n], acc[m][n], 0, 0, 0);
        __builtin_amdgcn_s_setprio(0);
        BARX();
    }

    #pragma unroll
    for (int mf = 0; mf < 4; ++mf) {
        const size_t row = m0 + wm*64 + mf*16 + hi*4;
        #pragma unroll
        for (int nf = 0; nf < 4; ++nf) {
            const size_t col = n0 + wn*64 + nf*16 + la;
            #pragma unroll
            for (int r = 0; r < 4; ++r) {
                const size_t off = (row + r) * (size_t)DH + col;
                outf[off] = x[off] + acc[mf][nf][r];
            }
        }
    }
}

// ---------------- RoPE table ----------------
__global__ __launch_bounds__(256) void rope_table(float* __restrict__ ctab,
                                                  float* __restrict__ stab) {
    int idx = blockIdx.x * 256 + threadIdx.x;
    int l = idx >> 6, i = idx & 63;
    float inv = powf(10000.0f, -(float)i / 64.0f);
    float ang = (float)l * inv;
    float s, c;
    sincosf(ang, &s, &c);
    ctab[idx] = c; stab[idx] = s;
}

__device__ __forceinline__ u32 rope_pair(u32 u, float c, float s) {
    float t1 = bf2f((u16)(u & 0xffff));
    float t2 = bf2f((u16)(u >> 16));
    float r1 = t1 * c - t2 * s;
    float r2 = t1 * s + t2 * c;
    bf16 b1 = (bf16)r1, b2 = (bf16)r2;
    return (u32)__builtin_bit_cast(u16, b1) | ((u32)__builtin_bit_cast(u16, b2) << 16);
}

// ---------------- q/k rope + reshape to [B,H,L,128] (h stride 6144) ----------------
__global__ __launch_bounds__(256) void rope_qk(const bf16* __restrict__ h,
                                               const float* __restrict__ ctab,
                                               const float* __restrict__ stab,
                                               bf16* __restrict__ qb, bf16* __restrict__ kb) {
    int idx = blockIdx.x * 256 + threadIdx.x;
    int i  = idx & 63;
    int hh = (idx >> 6) & 15;
    int l  = (idx >> 10) & 2047;
    int b  = idx >> 21;
    size_t hrow = (size_t)(b * SEQ + l) * HQKV;
    float c = ctab[l*64 + i], s = stab[l*64 + i];
    u32 uq = *(const u32*)(h + hrow + hh*DQ + 2*i);
    u32 uk = *(const u32*)(h + hrow + DH + hh*DQ + 2*i);
    size_t orow = ((size_t)(b*NH + hh) * SEQ + l) * DQ + 2*i;
    *(u32*)(qb + orow) = rope_pair(uq, c, s);
    *(u32*)(kb + orow) = rope_pair(uk, c, s);
}

// ---------------- V transpose (h stride 6144) -> vt [B,H,128,L] ----------------
__global__ __launch_bounds__(256) void v_transpose(const bf16* __restrict__ h,
                                                   bf16* __restrict__ vt) {
    __shared__ u32 lds[64][68];
    const int lt = blockIdx.x, bh = blockIdx.y;
    const int b = bh >> 4, hh = bh & 15;
    const int t = threadIdx.x;
    const bf16* src = h + (size_t)(b * SEQ + lt * 64) * HQKV + 2*DH + hh * DQ;
    #pragma unroll
    for (int i = 0; i < 4; ++i) {
        int j = i*256 + t;
        int l = j >> 4, ch = j & 15;
        uint4 v = *(const uint4*)(src + (size_t)l * HQKV + ch*8);
        *(uint4*)&lds[l][ch*4] = v;
    }
    __syncthreads();
    bf16* dst = vt + (size_t)bh * DQ * SEQ + lt * 64;
    #pragma unroll
    for (int i = 0; i < 4; ++i) {
        int j = i*256 + t;
        int d = j >> 3, lc = j & 7;
        u32 out[4];
        #pragma unroll
        for (int m = 0; m < 4; ++m) {
            u32 a0 = lds[lc*8 + 2*m][d >> 1];
            u32 a1 = lds[lc*8 + 2*m + 1][d >> 1];
            u16 s0 = (d & 1) ? (u16)(a0 >> 16) : (u16)(a0 & 0xffff);
            u16 s1 = (d & 1) ? (u16)(a1 >> 16) : (u16)(a1 & 0xffff);
            out[m] = (u32)s0 | ((u32)s1 << 16);
        }
        *(uint4*)(dst + (size_t)d * SEQ + lc*8) = *(uint4*)out;
    }
}

// ---------------- causal flash attention ----------------
__global__ __launch_bounds__(256) void attn_fa(const bf16* __restrict__ Q,
                                               const bf16* __restrict__ Kb,
                                               const bf16* __restrict__ Vt,
                                               bf16* __restrict__ O) {
    __shared__ bf16 Ks[64][128];
    __shared__ bf16 Vts[128][64];
    __shared__ bf16 Ps[4][16][64];
    const int qt = blockIdx.x, bh = blockIdx.y;
    const int b = bh >> 4, hh = bh & 15;
    const int tid = threadIdx.x, wid = tid >> 6, lane = tid & 63;
    const int la = lane & 15, hi = lane >> 4;
    const bf16* Qp = Q + (size_t)bh * SEQ * DQ;
    const bf16* Kp = Kb + (size_t)bh * SEQ * DQ;
    const bf16* Vp = Vt + (size_t)bh * DQ * SEQ;
    const int q0w = qt * 64 + wid * 16;

    bf16x8 qf[4];
    #pragma unroll
    for (int s = 0; s < 4; ++s)
        qf[s] = *(const bf16x8*)(Qp + (size_t)(q0w + la) * DQ + s*32 + hi*8);

    f32x4 acc_o[8] = {};
    float m_run[4] = {-1e30f, -1e30f, -1e30f, -1e30f};
    float l_run[4] = {0.f, 0.f, 0.f, 0.f};
    const float scale = 0.08838834764831845f;

    const int nk = qt + 1;
    for (int kt = 0; kt < nk; ++kt) {
        const int k0 = kt * 64;
        __syncthreads();
        #pragma unroll
        for (int i = 0; i < 4; ++i) {
            int j = i*256 + tid;
            int kr = j >> 4, jg = j & 15;
            gload16(Kp + (size_t)(k0 + kr) * DQ + ((jg ^ (kr & 7)) << 3),
                    (char*)Ks + i*4096 + wid*1024);
            int d = j >> 3, vg = j & 7;
            gload16(Vp + (size_t)d * SEQ + k0 + ((vg ^ (d & 7)) << 3),
                    (char*)Vts + i*4096 + wid*1024);
        }
        __syncthreads();

        f32x4 sacc[4] = {};
        __builtin_amdgcn_s_setprio(1);
        #pragma unroll
        for (int g = 0; g < 4; ++g) {
            const int krow = g*16 + la;
            #pragma unroll
            for (int s = 0; s < 4; ++s) {
                bf16x8 kf = *(const bf16x8*)((const char*)Ks + krow*256 + (((s*4 + hi) ^ (la & 7)) << 4));
                sacc[g] = __builtin_amdgcn_mfma_f32_16x16x32_bf16(qf[s], kf, sacc[g], 0, 0, 0);
            }
        }
        __builtin_amdgcn_s_setprio(0);

        float mnew[4];
        #pragma unroll
        for (int r = 0; r < 4; ++r) mnew[r] = m_run[r];
        #pragma unroll
        for (int g = 0; g < 4; ++g)
            #pragma unroll
            for (int r = 0; r < 4; ++r) {
                float sv = sacc[g][r] * scale;
                int qi = q0w + hi*4 + r;
                int ki = k0 + g*16 + la;
                sv = (ki <= qi) ? sv : -1e30f;
                sacc[g][r] = sv;
                mnew[r] = fmaxf(mnew[r], sv);
            }
        #pragma unroll
        for (int r = 0; r < 4; ++r) {
            float v = mnew[r];
            v = fmaxf(v, __shfl_xor(v, 1));
            v = fmaxf(v, __shfl_xor(v, 2));
            v = fmaxf(v, __shfl_xor(v, 4));
            v = fmaxf(v, __shfl_xor(v, 8));
            mnew[r] = v;
        }
        float resc[4], lsum[4];
        #pragma unroll
        for (int r = 0; r < 4; ++r) {
            resc[r] = __expf(m_run[r] - mnew[r]);
            m_run[r] = mnew[r];
            lsum[r] = 0.f;
        }
        #pragma unroll
        for (int g = 0; g < 4; ++g)
            #pragma unroll
            for (int r = 0; r < 4; ++r) {
                float p = __expf(sacc[g][r] - mnew[r]);
                sacc[g][r] = p;
                lsum[r] += p;
            }
        #pragma unroll
        for (int r = 0; r < 4; ++r) {
            float v = lsum[r];
            v += __shfl_xor(v, 1); v += __shfl_xor(v, 2);
            v += __shfl_xor(v, 4); v += __shfl_xor(v, 8);
            l_run[r] = l_run[r] * resc[r] + v;
        }
        #pragma unroll
        for (int g = 0; g < 4; ++g)
            #pragma unroll
            for (int r = 0; r < 4; ++r) {
                int prow = hi*4 + r;
                int pcol = (g*16 + la) ^ ((prow & 7) << 3);
                Ps[wid][prow][pcol] = (bf16)sacc[g][r];
            }
        #pragma unroll
        for (int n = 0; n < 8; ++n)
            #pragma unroll
            for (int r = 0; r < 4; ++r) acc_o[n][r] *= resc[r];
        __builtin_amdgcn_s_setprio(1);
        #pragma unroll
        for (int kk = 0; kk < 2; ++kk) {
            bf16x8 pf = *(const bf16x8*)((const char*)&Ps[wid][0][0] + la*128 +
                                         (((kk*32 + hi*8) ^ ((la & 7) << 3)) << 1));
            #pragma unroll
            for (int n = 0; n < 8; ++n) {
                const int vrow = n*16 + la;
                bf16x8 vf = *(const bf16x8*)((const char*)Vts + vrow*128 + (((kk*4 + hi) ^ (la & 7)) << 4));
                acc_o[n] = __builtin_amdgcn_mfma_f32_16x16x32_bf16(pf, vf, acc_o[n], 0, 0, 0);
            }
        }
        __builtin_amdgcn_s_setprio(0);
    }

    bf16* Op = O + (size_t)b * SEQ * DH + (size_t)hh * DQ;
    #pragma unroll
    for (int r = 0; r < 4; ++r) {
        int qi = q0w + hi*4 + r;
        float invl = 1.0f / l_run[r];
        #pragma unroll
        for (int n = 0; n < 8; ++n)
            Op[(size_t)qi * DH + n*16 + la] = (bf16)(acc_o[n][r] * invl);
    }
}

// ---------------- launch ----------------
extern "C" void kernel_launch(void* const* d_in, const int* in_sizes, int n_in,
                              void* d_out, int out_size, void* d_ws, size_t ws_size,
                              hipStream_t stream) {
    const float* x       = (const float*)d_in[0];
    const float* g       = (const float*)d_in[1];
    const float* W_dense = (const float*)d_in[2];
    const float* b_dense = (const float*)d_in[3];
    const float* W_attn  = (const float*)d_in[4];
    const float* W_ffn   = (const float*)d_in[5];
    float* out = (float*)d_out;

    char* ws = (char*)d_ws;
    bf16* normed  = (bf16*)(ws + 0);                    // 16.8 MB (reused as attn_buf)
    bf16* Wd_b    = (bf16*)(ws + 16777216);             // 92.3 MB (reused as q/k/vt)
    bf16* Wa_b    = (bf16*)(ws + 109051904);            // 8.4 MB
    bf16* Wf_b    = (bf16*)(ws + 117440512);            // 33.6 MB
    bf16* h_b     = (bf16*)(ws + 150994944);            // 50.3 MB (qkv only, stride 6144)
    bf16* ag_b    = (bf16*)(ws + 335544320);            // 67.1 MB
    float* ctab   = (float*)(ws + 402653184);           // 0.5 MB
    float* stab   = (float*)(ws + 403177472);           // 0.5 MB
    bf16* q_b  = (bf16*)(ws + 16777216);
    bf16* k_b  = (bf16*)(ws + 16777216 + 16777216);
    bf16* vt_b = (bf16*)(ws + 16777216 + 33554432);
    bf16* attn_b = normed;

    cvt_wd<<<46137344/2048, 256, 0, stream>>>(W_dense, Wd_b);
    cvt_f32_bf16<<<4194304/2048, 256, 0, stream>>>(W_attn, Wa_b);
    cvt_f32_bf16<<<16777216/2048, 256, 0, stream>>>(W_ffn, Wf_b);
    rmsnorm_k<<<NROWS, 256, 0, stream>>>(x, g, normed);
    // dense GEMM -> h6 (qkv) + ag (fused SwiGLU)
    {
        dim3 grid((NROWS/256) * (DOUT/256));            // 1408, %8==0
        gemm_dense<<<grid, 512, 0, stream>>>(normed, Wd_b, b_dense, h_b, ag_b);
    }
    rope_table<<<SEQ*64/256, 256, 0, stream>>>(ctab, stab);
    rope_qk<<<4194304/256, 256, 0, stream>>>(h_b, ctab, stab, q_b, k_b);
    {
        dim3 grid(SEQ/64, BATCH*NH);
        v_transpose<<<grid, 256, 0, stream>>>(h_b, vt_b);
    }
    {
        dim3 grid(SEQ/64, BATCH*NH);
        attn_fa<<<grid, 256, 0, stream>>>(q_b, k_b, vt_b, attn_b);
    }
    // fused: out = x + attn.Wa^T + ag.Wf^T
    gemm_out<<<256, 512, 0, stream>>>(attn_b, Wa_b, ag_b, Wf_b, x, out);
}